// Round 1
// baseline (1200.981 us; speedup 1.0000x reference)
//
#include <hip/hip_runtime.h>
#include <hip/hip_bf16.h>

#define NT 4           // node types (labels)
#define FEAT 256       // nfeat == nhid
#define OUT3 64        // nclass

typedef __bf16 bf16x8 __attribute__((ext_vector_type(8)));
typedef float  f32x4  __attribute__((ext_vector_type(4)));

__device__ inline unsigned int f2bf_bits(float f) {
    __hip_bfloat16 h = __float2bfloat16(f);   // RNE
    unsigned short u;
    __builtin_memcpy(&u, &h, 2);
    return (unsigned int)u;
}

// ---------------- init: zero counters, fill perm with -1 ----------------
__global__ void init_kernel(int* __restrict__ deg, int* __restrict__ cursor,
                            int* __restrict__ perm, int* __restrict__ lc,
                            int* __restrict__ lcur, int N, int permCap) {
    int i = blockIdx.x * 256 + threadIdx.x;
    if (i < N) { deg[i] = 0; cursor[i] = 0; }
    if (i < permCap) perm[i] = -1;
    if (i < NT) { lc[i] = 0; lcur[i] = 0; }
}

// ---------------- label histogram (wave-aggregated atomics) ----------------
__global__ void hist_labels(const int* __restrict__ labels, int* __restrict__ lc, int N) {
    int n = blockIdx.x * 256 + threadIdx.x;
    int lab = (n < N) ? labels[n] : -1;
    int lane = threadIdx.x & 63;
    for (int l = 0; l < NT; ++l) {
        unsigned long long m = __ballot(lab == l);
        if (m == 0ull) continue;
        if (lane == __builtin_ctzll(m)) atomicAdd(&lc[l], (int)__popcll(m));
    }
}

// ---------------- edge histogram by dst ----------------
__global__ void hist_edges(const int* __restrict__ dst, int* __restrict__ deg, int E) {
    int e = blockIdx.x * 256 + threadIdx.x;
    if (e < E) atomicAdd(&deg[dst[e]], 1);
}

// ---------------- exclusive scan of deg -> rowoff (single block) ----------------
__global__ void scan_kernel(const int* __restrict__ deg, int* __restrict__ rowoff, int N) {
    __shared__ int sums[256];
    int tid = threadIdx.x;
    int per = (N + 255) >> 8;
    int s0 = tid * per, s1 = s0 + per; if (s1 > N) s1 = N;
    int s = 0;
    for (int i = s0; i < s1; ++i) s += deg[i];
    sums[tid] = s;
    __syncthreads();
    if (tid == 0) {
        int run = 0;
        for (int j = 0; j < 256; ++j) { int t = sums[j]; sums[j] = run; run += t; }
        rowoff[N] = run;
    }
    __syncthreads();
    int run = sums[tid];
    for (int i = s0; i < s1; ++i) { rowoff[i] = run; run += deg[i]; }
}

// ---------------- label region starts (padded to 16) ----------------
__global__ void label_start_kernel(const int* __restrict__ lc, int* __restrict__ lstart) {
    if (threadIdx.x == 0 && blockIdx.x == 0) {
        int run = 0;
        for (int l = 0; l < NT; ++l) { lstart[l] = run; run += (lc[l] + 15) & ~15; }
    }
}

// ---------------- scatter nodes into label-sorted perm ----------------
__global__ void scatter_nodes(const int* __restrict__ labels, const int* __restrict__ lstart,
                              int* __restrict__ lcur, int* __restrict__ perm, int N) {
    int n = blockIdx.x * 256 + threadIdx.x;
    int lab = (n < N) ? labels[n] : -1;
    int lane = threadIdx.x & 63;
    for (int l = 0; l < NT; ++l) {
        unsigned long long m = __ballot(lab == l);
        if (m == 0ull) continue;
        int leader = __builtin_ctzll(m);
        int base = 0;
        if (lane == leader) base = atomicAdd(&lcur[l], (int)__popcll(m));
        base = __shfl(base, leader, 64);
        if (lab == l) {
            int prefix = (int)__popcll(m & ((1ull << lane) - 1ull));
            perm[lstart[l] + base + prefix] = n;
        }
    }
}

// ---------------- scatter edges into CSR order ----------------
__global__ void scatter_edges(const int* __restrict__ src, const int* __restrict__ dst,
                              const float* __restrict__ w, const int* __restrict__ rowoff,
                              int* __restrict__ cursor, int* __restrict__ ssrc,
                              float* __restrict__ sw, int E) {
    int e = blockIdx.x * 256 + threadIdx.x;
    if (e < E) {
        int d = dst[e];
        int pos = rowoff[d] + atomicAdd(&cursor[d], 1);
        ssrc[pos] = src[e];
        sw[pos] = w[e];
    }
}

// ---------------- cast x (fp32) -> bf16, vectorized ----------------
__global__ void cast_x(const float* __restrict__ x, unsigned short* __restrict__ xb, int total4) {
    int i = blockIdx.x * 256 + threadIdx.x;
    if (i < total4) {
        const float4* xv = (const float4*)x;
        float4 v = xv[i];
        unsigned int lo = f2bf_bits(v.x) | (f2bf_bits(v.y) << 16);
        unsigned int hi = f2bf_bits(v.z) | (f2bf_bits(v.w) << 16);
        uint2 o; o.x = lo; o.y = hi;
        ((uint2*)xb)[i] = o;
    }
}

// ---------------- cast W (fp32) -> bf16 in B-fragment swizzled layout ----------------
// Wswz index: (((lab*8 + k0)*OUTF + n)*4 + q)*8 + j ; element = W[lab][k0*32+q*8+j][n]
__global__ void cast_w(const float* __restrict__ W, unsigned short* __restrict__ Wswz,
                       int OUTF, int total) {
    int idx = blockIdx.x * 256 + threadIdx.x;
    if (idx < total) {
        int n = idx % OUTF;
        int r = idx / OUTF;          // = lab*256 + k  (k = k0*32+q*8+j)
        int j = r & 7, q = (r >> 3) & 3, k0 = (r >> 5) & 7, lab = r >> 8;
        int k = k0 * 32 + q * 8 + j;
        float f = W[((size_t)(lab * FEAT + k)) * OUTF + n];
        Wswz[((((size_t)lab * 8 + k0) * OUTF + n) * 4 + q) * 8 + j] = (unsigned short)f2bf_bits(f);
    }
}

// ---------------- projection: support = x @ W[label[node]]  (bf16 MFMA) ----------------
// Each wave: 16 nodes x 64 outs (4 accumulator tiles of 16x16), K=256 in 8 steps of 32.
template <int OUTF>
__global__ __launch_bounds__(256) void proj_kernel(
    const unsigned short* __restrict__ xb, const unsigned short* __restrict__ Wswz,
    const int* __restrict__ perm, const int* __restrict__ labels,
    unsigned short* __restrict__ outp, int groups) {
    int warp = threadIdx.x >> 6;
    int lane = threadIdx.x & 63;
    int gm, n0;
    if constexpr (OUTF == 256) { gm = blockIdx.x; n0 = warp * 64; }
    else { gm = blockIdx.x * 4 + warp; n0 = 0; if (gm >= groups) return; }
    int m0 = gm * 16;
    int first = perm[m0];
    if (first < 0) return;                    // all-pad group
    int lab = labels[first];                  // uniform within group by construction
    int q = lane >> 4, c = lane & 15;
    int nodeA = perm[m0 + c];
    int ndA = (nodeA < 0) ? first : nodeA;    // pad rows: load a valid row, never stored

    const bf16x8* aptr = (const bf16x8*)(xb + (size_t)ndA * FEAT + q * 8);
    const unsigned short* bb = Wswz + (size_t)lab * FEAT * OUTF + (size_t)(n0 + c) * 32 + q * 8;

    f32x4 acc[4] = {};
#pragma unroll
    for (int k0 = 0; k0 < 8; ++k0) {
        bf16x8 a = aptr[k0 * 4];
        const unsigned short* bk = bb + (size_t)k0 * 32 * OUTF;
#pragma unroll
        for (int t = 0; t < 4; ++t) {
            bf16x8 b = *(const bf16x8*)(bk + t * 512);
            acc[t] = __builtin_amdgcn_mfma_f32_16x16x32_bf16(a, b, acc[t], 0, 0, 0);
        }
    }
    // C/D layout: row=(lane>>4)*4+reg, col=lane&15
    __hip_bfloat16* ob = (__hip_bfloat16*)outp;
#pragma unroll
    for (int r = 0; r < 4; ++r) {
        int noder = perm[m0 + q * 4 + r];
        if (noder >= 0) {
#pragma unroll
            for (int t = 0; t < 4; ++t)
                ob[(size_t)noder * OUTF + n0 + t * 16 + c] = __float2bfloat16(acc[t][r]);
        }
    }
}

// ---------------- aggregation: out[n] = [relu](sum_e w*support[src] + bias) ----------------
template <int OUTF, bool RELU, bool FP32OUT>
__global__ __launch_bounds__(256) void agg_kernel(
    const unsigned short* __restrict__ sup, const int* __restrict__ rowoff,
    const int* __restrict__ ssrc, const float* __restrict__ sw,
    const float* __restrict__ bias, void* __restrict__ outp, int N) {
    constexpr int TPN = OUTF / 2;       // threads per node (2 feats/thread)
    constexpr int NPB = 256 / TPN;      // nodes per block
    int g = threadIdx.x / TPN;
    int tt = threadIdx.x % TPN;
    int node = blockIdx.x * NPB + g;
    if (node >= N) return;
    int s = rowoff[node], e = rowoff[node + 1];
    float a0 = 0.f, a1 = 0.f;
    const unsigned int* supv = (const unsigned int*)sup;
    for (int i = s; i < e; ++i) {
        int src = ssrc[i];
        float w = sw[i];
        unsigned int v = supv[(size_t)src * TPN + tt];
        a0 += w * __uint_as_float(v << 16);
        a1 += w * __uint_as_float(v & 0xffff0000u);
    }
    a0 += bias[2 * tt];
    a1 += bias[2 * tt + 1];
    if (RELU) { a0 = fmaxf(a0, 0.f); a1 = fmaxf(a1, 0.f); }
    if constexpr (FP32OUT) {
        float2 o; o.x = a0; o.y = a1;
        ((float2*)outp)[(size_t)node * TPN + tt] = o;
    } else {
        ((unsigned int*)outp)[(size_t)node * TPN + tt] = f2bf_bits(a0) | (f2bf_bits(a1) << 16);
    }
}

extern "C" void kernel_launch(void* const* d_in, const int* in_sizes, int n_in,
                              void* d_out, int out_size, void* d_ws, size_t ws_size,
                              hipStream_t stream) {
    const float* x        = (const float*)d_in[0];
    const int*   edge_src = (const int*)d_in[1];
    const int*   edge_dst = (const int*)d_in[2];
    const float* edge_w   = (const float*)d_in[3];
    const int*   labels   = (const int*)d_in[4];
    const float* W1 = (const float*)d_in[5];
    const float* b1 = (const float*)d_in[6];
    const float* W2 = (const float*)d_in[7];
    const float* b2 = (const float*)d_in[8];
    const float* W3 = (const float*)d_in[9];
    const float* b3 = (const float*)d_in[10];

    const int N = in_sizes[0] / FEAT;
    const int E = in_sizes[1];
    const int groups  = (N + NT * 16 + 15) / 16;   // 16-node tiles incl. per-label padding
    const int permCap = groups * 16;

    // ---- workspace carve (256B aligned) ----
    char* p = (char*)d_ws;
    auto alloc = [&](size_t bytes) -> char* {
        char* r = p;
        p += (bytes + 255) & ~(size_t)255;
        return r;
    };
    unsigned short* bufA = (unsigned short*)alloc((size_t)N * FEAT * 2);
    unsigned short* bufB = (unsigned short*)alloc((size_t)N * FEAT * 2);
    unsigned short* W1b  = (unsigned short*)alloc((size_t)NT * FEAT * FEAT * 2);
    unsigned short* W2b  = (unsigned short*)alloc((size_t)NT * FEAT * FEAT * 2);
    unsigned short* W3b  = (unsigned short*)alloc((size_t)NT * FEAT * OUT3 * 2);
    int*   rowoff = (int*)alloc((size_t)(N + 1) * 4);
    int*   deg    = (int*)alloc((size_t)N * 4);
    int*   cursor = (int*)alloc((size_t)N * 4);
    int*   ssrc   = (int*)alloc((size_t)E * 4);
    float* sw     = (float*)alloc((size_t)E * 4);
    int*   perm   = (int*)alloc((size_t)permCap * 4);
    int*   lc     = (int*)alloc(64);
    int*   lcur   = (int*)alloc(64);
    int*   lstart = (int*)alloc(64);

    // ---- CSR + label-sort build ----
    init_kernel<<<(permCap + 255) / 256, 256, 0, stream>>>(deg, cursor, perm, lc, lcur, N, permCap);
    hist_labels<<<(N + 255) / 256, 256, 0, stream>>>(labels, lc, N);
    hist_edges<<<(E + 255) / 256, 256, 0, stream>>>(edge_dst, deg, E);
    scan_kernel<<<1, 256, 0, stream>>>(deg, rowoff, N);
    label_start_kernel<<<1, 64, 0, stream>>>(lc, lstart);
    scatter_nodes<<<(N + 255) / 256, 256, 0, stream>>>(labels, lstart, lcur, perm, N);
    scatter_edges<<<(E + 255) / 256, 256, 0, stream>>>(edge_src, edge_dst, edge_w, rowoff, cursor, ssrc, sw, E);

    // ---- casts ----
    cast_x<<<((N * FEAT / 4) + 255) / 256, 256, 0, stream>>>(x, bufA, N * FEAT / 4);
    cast_w<<<((NT * FEAT * FEAT) + 255) / 256, 256, 0, stream>>>(W1, W1b, FEAT, NT * FEAT * FEAT);
    cast_w<<<((NT * FEAT * FEAT) + 255) / 256, 256, 0, stream>>>(W2, W2b, FEAT, NT * FEAT * FEAT);
    cast_w<<<((NT * FEAT * OUT3) + 255) / 256, 256, 0, stream>>>(W3, W3b, OUT3, NT * FEAT * OUT3);

    // ---- layer 1 ----
    proj_kernel<256><<<groups, 256, 0, stream>>>(bufA, W1b, perm, labels, bufB, groups);
    agg_kernel<256, true, false><<<(N + 1) / 2, 256, 0, stream>>>(bufB, rowoff, ssrc, sw, b1, bufA, N);
    // ---- layer 2 ----
    proj_kernel<256><<<groups, 256, 0, stream>>>(bufA, W2b, perm, labels, bufB, groups);
    agg_kernel<256, true, false><<<(N + 1) / 2, 256, 0, stream>>>(bufB, rowoff, ssrc, sw, b2, bufA, N);
    // ---- layer 3 ----
    proj_kernel<64><<<(groups + 3) / 4, 256, 0, stream>>>(bufA, W3b, perm, labels, bufB, groups);
    agg_kernel<64, false, true><<<(N + 7) / 8, 256, 0, stream>>>(bufB, rowoff, ssrc, sw, b3, d_out, N);
}

// Round 2
// 770.297 us; speedup vs baseline: 1.5591x; 1.5591x over previous
//
#include <hip/hip_runtime.h>
#include <hip/hip_bf16.h>

#define NT 4           // node types (labels)
#define FEAT 256       // nfeat == nhid
#define OUT3 64        // nclass

typedef __bf16 bf16x8 __attribute__((ext_vector_type(8)));
typedef float  f32x4  __attribute__((ext_vector_type(4)));

__device__ inline unsigned int f2bf_bits(float f) {
    __hip_bfloat16 h = __float2bfloat16(f);   // RNE
    unsigned short u;
    __builtin_memcpy(&u, &h, 2);
    return (unsigned int)u;
}
__device__ inline float bfl(unsigned int u) { return __uint_as_float(u << 16); }
__device__ inline float bfh(unsigned int u) { return __uint_as_float(u & 0xffff0000u); }

// ---------------- init: zero counters, fill perm with -1 ----------------
__global__ void init_kernel(int* __restrict__ deg, int* __restrict__ cursor,
                            int* __restrict__ perm, int* __restrict__ lc,
                            int* __restrict__ lcur, int N, int permCap) {
    int i = blockIdx.x * 256 + threadIdx.x;
    if (i < N) { deg[i] = 0; cursor[i] = 0; }
    if (i < permCap) perm[i] = -1;
    if (i < NT) { lc[i] = 0; lcur[i] = 0; }
}

// ---------------- label histogram (wave-aggregated atomics) ----------------
__global__ void hist_labels(const int* __restrict__ labels, int* __restrict__ lc, int N) {
    int n = blockIdx.x * 256 + threadIdx.x;
    int lab = (n < N) ? labels[n] : -1;
    int lane = threadIdx.x & 63;
    for (int l = 0; l < NT; ++l) {
        unsigned long long m = __ballot(lab == l);
        if (m == 0ull) continue;
        if (lane == __builtin_ctzll(m)) atomicAdd(&lc[l], (int)__popcll(m));
    }
}

// ---------------- edge histogram by dst ----------------
__global__ void hist_edges(const int* __restrict__ dst, int* __restrict__ deg, int E) {
    int e = blockIdx.x * 256 + threadIdx.x;
    if (e < E) atomicAdd(&deg[dst[e]], 1);
}

// ---------------- exclusive scan of deg -> rowoff (1024 thr + wave scan) ----------------
__global__ __launch_bounds__(1024) void scan_kernel(const int* __restrict__ deg,
                                                    int* __restrict__ rowoff, int N) {
    __shared__ int sums[1024];
    int tid = threadIdx.x;
    int per = (N + 1023) >> 10;
    int s0 = tid * per, s1 = s0 + per; if (s1 > N) s1 = N;
    int s = 0;
    for (int i = s0; i < s1; ++i) s += deg[i];
    sums[tid] = s;
    __syncthreads();
    if (tid < 64) {
        int base = tid * 16;
        int tot = 0;
#pragma unroll
        for (int k = 0; k < 16; ++k) tot += sums[base + k];
        // inclusive wave scan of tot
        int v = tot;
#pragma unroll
        for (int d = 1; d < 64; d <<= 1) {
            int u = __shfl_up(v, d, 64);
            if (tid >= d) v += u;
        }
        if (tid == 63) rowoff[N] = v;
        int run = v - tot;   // exclusive prefix
#pragma unroll
        for (int k = 0; k < 16; ++k) { int t = sums[base + k]; sums[base + k] = run; run += t; }
    }
    __syncthreads();
    int run = sums[tid];
    for (int i = s0; i < s1; ++i) { rowoff[i] = run; run += deg[i]; }
}

// ---------------- label region starts (padded to 16) ----------------
__global__ void label_start_kernel(const int* __restrict__ lc, int* __restrict__ lstart) {
    if (threadIdx.x == 0 && blockIdx.x == 0) {
        int run = 0;
        for (int l = 0; l < NT; ++l) { lstart[l] = run; run += (lc[l] + 15) & ~15; }
    }
}

// ---------------- scatter nodes into label-sorted perm ----------------
__global__ void scatter_nodes(const int* __restrict__ labels, const int* __restrict__ lstart,
                              int* __restrict__ lcur, int* __restrict__ perm, int N) {
    int n = blockIdx.x * 256 + threadIdx.x;
    int lab = (n < N) ? labels[n] : -1;
    int lane = threadIdx.x & 63;
    for (int l = 0; l < NT; ++l) {
        unsigned long long m = __ballot(lab == l);
        if (m == 0ull) continue;
        int leader = __builtin_ctzll(m);
        int base = 0;
        if (lane == leader) base = atomicAdd(&lcur[l], (int)__popcll(m));
        base = __shfl(base, leader, 64);
        if (lab == l) {
            int prefix = (int)__popcll(m & ((1ull << lane) - 1ull));
            perm[lstart[l] + base + prefix] = n;
        }
    }
}

// ---------------- scatter edges into CSR order: edata[pos] = (src, w_bits) ----------------
__global__ void scatter_edges(const int* __restrict__ src, const int* __restrict__ dst,
                              const float* __restrict__ w, const int* __restrict__ rowoff,
                              int* __restrict__ cursor, uint2* __restrict__ edata, int E) {
    int e = blockIdx.x * 256 + threadIdx.x;
    if (e < E) {
        int d = dst[e];
        int pos = rowoff[d] + atomicAdd(&cursor[d], 1);
        edata[pos] = make_uint2((unsigned int)src[e], __float_as_uint(w[e]));
    }
}

// ---------------- cast x (fp32) -> bf16, vectorized ----------------
__global__ void cast_x(const float* __restrict__ x, unsigned short* __restrict__ xb, int total4) {
    int i = blockIdx.x * 256 + threadIdx.x;
    if (i < total4) {
        const float4* xv = (const float4*)x;
        float4 v = xv[i];
        unsigned int lo = f2bf_bits(v.x) | (f2bf_bits(v.y) << 16);
        unsigned int hi = f2bf_bits(v.z) | (f2bf_bits(v.w) << 16);
        uint2 o; o.x = lo; o.y = hi;
        ((uint2*)xb)[i] = o;
    }
}

// ---------------- cast W (fp32) -> bf16 in B-fragment swizzled layout ----------------
// Wswz index: (((lab*8 + k0)*OUTF + n)*4 + q)*8 + j ; element = W[lab][k0*32+q*8+j][n]
__global__ void cast_w(const float* __restrict__ W, unsigned short* __restrict__ Wswz,
                       int OUTF, int total) {
    int idx = blockIdx.x * 256 + threadIdx.x;
    if (idx < total) {
        int n = idx % OUTF;
        int r = idx / OUTF;          // = lab*256 + k  (k = k0*32+q*8+j)
        int j = r & 7, q = (r >> 3) & 3, k0 = (r >> 5) & 7, lab = r >> 8;
        int k = k0 * 32 + q * 8 + j;
        float f = W[((size_t)(lab * FEAT + k)) * OUTF + n];
        Wswz[((((size_t)lab * 8 + k0) * OUTF + n) * 4 + q) * 8 + j] = (unsigned short)f2bf_bits(f);
    }
}

// ---------------- projection: support = x @ W[label[node]]  (bf16 MFMA) ----------------
template <int OUTF>
__global__ __launch_bounds__(256) void proj_kernel(
    const unsigned short* __restrict__ xb, const unsigned short* __restrict__ Wswz,
    const int* __restrict__ perm, const int* __restrict__ labels,
    unsigned short* __restrict__ outp, int groups) {
    int warp = threadIdx.x >> 6;
    int lane = threadIdx.x & 63;
    int gm, n0;
    if constexpr (OUTF == 256) { gm = blockIdx.x; n0 = warp * 64; }
    else { gm = blockIdx.x * 4 + warp; n0 = 0; if (gm >= groups) return; }
    int m0 = gm * 16;
    int first = perm[m0];
    if (first < 0) return;                    // all-pad group
    int lab = labels[first];                  // uniform within group by construction
    int q = lane >> 4, c = lane & 15;
    int nodeA = perm[m0 + c];
    int ndA = (nodeA < 0) ? first : nodeA;    // pad rows: load a valid row, never stored

    const bf16x8* aptr = (const bf16x8*)(xb + (size_t)ndA * FEAT + q * 8);
    const unsigned short* bb = Wswz + (size_t)lab * FEAT * OUTF + (size_t)(n0 + c) * 32 + q * 8;

    f32x4 acc[4] = {};
#pragma unroll
    for (int k0 = 0; k0 < 8; ++k0) {
        bf16x8 a = aptr[k0 * 4];
        const unsigned short* bk = bb + (size_t)k0 * 32 * OUTF;
#pragma unroll
        for (int t = 0; t < 4; ++t) {
            bf16x8 b = *(const bf16x8*)(bk + t * 512);
            acc[t] = __builtin_amdgcn_mfma_f32_16x16x32_bf16(a, b, acc[t], 0, 0, 0);
        }
    }
    // C/D layout: row=(lane>>4)*4+reg, col=lane&15
    __hip_bfloat16* ob = (__hip_bfloat16*)outp;
#pragma unroll
    for (int r = 0; r < 4; ++r) {
        int noder = perm[m0 + q * 4 + r];
        if (noder >= 0) {
#pragma unroll
            for (int t = 0; t < 4; ++t)
                ob[(size_t)noder * OUTF + n0 + t * 16 + c] = __float2bfloat16(acc[t][r]);
        }
    }
}

// ---------------- aggregation, 256-feat: one wave per node ----------------
// lane holds feats [4*lane, 4*lane+4) as uint2 (4 bf16). Edge (src,w) broadcast by shfl.
__global__ __launch_bounds__(256) void agg256_kernel(
    const uint2* __restrict__ sup, const int* __restrict__ rowoff,
    const uint2* __restrict__ edata, const float* __restrict__ bias,
    uint2* __restrict__ outp, int N) {
    int node = (int)((blockIdx.x * 256 + threadIdx.x) >> 6);
    int lane = threadIdx.x & 63;
    if (node >= N) return;
    int s = rowoff[node], e = rowoff[node + 1];
    float a0 = 0.f, a1 = 0.f, a2 = 0.f, a3 = 0.f;
    for (int base = s; base < e; base += 64) {
        int cnt = e - base; if (cnt > 64) cnt = 64;
        int p = base + lane; if (p >= e) p = e - 1;
        uint2 ed = edata[p];
        for (int j = 0; j < cnt; j += 4) {
            int sk[4]; float wk[4];
#pragma unroll
            for (int u = 0; u < 4; ++u) {
                int jj = j + u;
                int jc = (jj < cnt) ? jj : cnt - 1;
                sk[u] = __shfl((int)ed.x, jc, 64);
                float w = __uint_as_float(__shfl((int)ed.y, jc, 64));
                wk[u] = (jj < cnt) ? w : 0.f;
            }
            uint2 v[4];
#pragma unroll
            for (int u = 0; u < 4; ++u) v[u] = sup[(size_t)sk[u] * 64 + lane];
#pragma unroll
            for (int u = 0; u < 4; ++u) {
                a0 += wk[u] * bfl(v[u].x);
                a1 += wk[u] * bfh(v[u].x);
                a2 += wk[u] * bfl(v[u].y);
                a3 += wk[u] * bfh(v[u].y);
            }
        }
    }
    float4 b = ((const float4*)bias)[lane];
    a0 = fmaxf(a0 + b.x, 0.f);
    a1 = fmaxf(a1 + b.y, 0.f);
    a2 = fmaxf(a2 + b.z, 0.f);
    a3 = fmaxf(a3 + b.w, 0.f);
    unsigned int lo = f2bf_bits(a0) | (f2bf_bits(a1) << 16);
    unsigned int hi = f2bf_bits(a2) | (f2bf_bits(a3) << 16);
    outp[(size_t)node * 64 + lane] = make_uint2(lo, hi);
}

// ---------------- aggregation, 64-feat: half-wave per node, fp32 out ----------------
// lane (within 32-group) holds feats [2*lane, 2*lane+2) as uint (2 bf16).
__global__ __launch_bounds__(256) void agg64_kernel(
    const unsigned int* __restrict__ sup, const int* __restrict__ rowoff,
    const uint2* __restrict__ edata, const float* __restrict__ bias,
    float2* __restrict__ outp, int N) {
    int node = (int)((blockIdx.x * 256 + threadIdx.x) >> 5);
    int lane = threadIdx.x & 31;
    if (node >= N) return;
    int s = rowoff[node], e = rowoff[node + 1];
    float a0 = 0.f, a1 = 0.f;
    for (int base = s; base < e; base += 32) {
        int cnt = e - base; if (cnt > 32) cnt = 32;
        int p = base + lane; if (p >= e) p = e - 1;
        uint2 ed = edata[p];
        for (int j = 0; j < cnt; j += 4) {
            int sk[4]; float wk[4];
#pragma unroll
            for (int u = 0; u < 4; ++u) {
                int jj = j + u;
                int jc = (jj < cnt) ? jj : cnt - 1;
                sk[u] = __shfl((int)ed.x, jc, 32);
                float w = __uint_as_float(__shfl((int)ed.y, jc, 32));
                wk[u] = (jj < cnt) ? w : 0.f;
            }
            unsigned int v[4];
#pragma unroll
            for (int u = 0; u < 4; ++u) v[u] = sup[(size_t)sk[u] * 32 + lane];
#pragma unroll
            for (int u = 0; u < 4; ++u) {
                a0 += wk[u] * bfl(v[u]);
                a1 += wk[u] * bfh(v[u]);
            }
        }
    }
    float2 b = ((const float2*)bias)[lane];
    float2 o; o.x = a0 + b.x; o.y = a1 + b.y;
    outp[(size_t)node * 32 + lane] = o;
}

extern "C" void kernel_launch(void* const* d_in, const int* in_sizes, int n_in,
                              void* d_out, int out_size, void* d_ws, size_t ws_size,
                              hipStream_t stream) {
    const float* x        = (const float*)d_in[0];
    const int*   edge_src = (const int*)d_in[1];
    const int*   edge_dst = (const int*)d_in[2];
    const float* edge_w   = (const float*)d_in[3];
    const int*   labels   = (const int*)d_in[4];
    const float* W1 = (const float*)d_in[5];
    const float* b1 = (const float*)d_in[6];
    const float* W2 = (const float*)d_in[7];
    const float* b2 = (const float*)d_in[8];
    const float* W3 = (const float*)d_in[9];
    const float* b3 = (const float*)d_in[10];

    const int N = in_sizes[0] / FEAT;
    const int E = in_sizes[1];
    const int groups  = (N + NT * 16 + 15) / 16;   // 16-node tiles incl. per-label padding
    const int permCap = groups * 16;

    // ---- workspace carve (256B aligned) ----
    char* p = (char*)d_ws;
    auto alloc = [&](size_t bytes) -> char* {
        char* r = p;
        p += (bytes + 255) & ~(size_t)255;
        return r;
    };
    unsigned short* bufA = (unsigned short*)alloc((size_t)N * FEAT * 2);
    unsigned short* bufB = (unsigned short*)alloc((size_t)N * FEAT * 2);
    unsigned short* W1b  = (unsigned short*)alloc((size_t)NT * FEAT * FEAT * 2);
    unsigned short* W2b  = (unsigned short*)alloc((size_t)NT * FEAT * FEAT * 2);
    unsigned short* W3b  = (unsigned short*)alloc((size_t)NT * FEAT * OUT3 * 2);
    int*   rowoff = (int*)alloc((size_t)(N + 1) * 4);
    int*   deg    = (int*)alloc((size_t)N * 4);
    int*   cursor = (int*)alloc((size_t)N * 4);
    uint2* edata  = (uint2*)alloc((size_t)E * 8);
    int*   perm   = (int*)alloc((size_t)permCap * 4);
    int*   lc     = (int*)alloc(64);
    int*   lcur   = (int*)alloc(64);
    int*   lstart = (int*)alloc(64);

    // ---- CSR + label-sort build ----
    init_kernel<<<(permCap + 255) / 256, 256, 0, stream>>>(deg, cursor, perm, lc, lcur, N, permCap);
    hist_labels<<<(N + 255) / 256, 256, 0, stream>>>(labels, lc, N);
    hist_edges<<<(E + 255) / 256, 256, 0, stream>>>(edge_dst, deg, E);
    scan_kernel<<<1, 1024, 0, stream>>>(deg, rowoff, N);
    label_start_kernel<<<1, 64, 0, stream>>>(lc, lstart);
    scatter_nodes<<<(N + 255) / 256, 256, 0, stream>>>(labels, lstart, lcur, perm, N);
    scatter_edges<<<(E + 255) / 256, 256, 0, stream>>>(edge_src, edge_dst, edge_w, rowoff, cursor, edata, E);

    // ---- casts ----
    cast_x<<<((N * FEAT / 4) + 255) / 256, 256, 0, stream>>>(x, bufA, N * FEAT / 4);
    cast_w<<<((NT * FEAT * FEAT) + 255) / 256, 256, 0, stream>>>(W1, W1b, FEAT, NT * FEAT * FEAT);
    cast_w<<<((NT * FEAT * FEAT) + 255) / 256, 256, 0, stream>>>(W2, W2b, FEAT, NT * FEAT * FEAT);
    cast_w<<<((NT * FEAT * OUT3) + 255) / 256, 256, 0, stream>>>(W3, W3b, OUT3, NT * FEAT * OUT3);

    // ---- layer 1 ----
    proj_kernel<256><<<groups, 256, 0, stream>>>(bufA, W1b, perm, labels, bufB, groups);
    agg256_kernel<<<(N + 3) / 4, 256, 0, stream>>>((const uint2*)bufB, rowoff, edata, b1, (uint2*)bufA, N);
    // ---- layer 2 ----
    proj_kernel<256><<<groups, 256, 0, stream>>>(bufA, W2b, perm, labels, bufB, groups);
    agg256_kernel<<<(N + 3) / 4, 256, 0, stream>>>((const uint2*)bufB, rowoff, edata, b2, (uint2*)bufA, N);
    // ---- layer 3 ----
    proj_kernel<64><<<(groups + 3) / 4, 256, 0, stream>>>(bufA, W3b, perm, labels, bufB, groups);
    agg64_kernel<<<(N + 7) / 8, 256, 0, stream>>>((const unsigned int*)bufB, rowoff, edata, b3, (float2*)d_out, N);
}

// Round 3
// 595.816 us; speedup vs baseline: 2.0157x; 1.2928x over previous
//
#include <hip/hip_runtime.h>
#include <hip/hip_bf16.h>

#define NT 4           // node types (labels)
#define FEAT 256       // nfeat == nhid
#define OUT3 64        // nclass

typedef __bf16 bf16x8 __attribute__((ext_vector_type(8)));
typedef float  f32x4  __attribute__((ext_vector_type(4)));

__device__ inline unsigned int f2bf_bits(float f) {
    __hip_bfloat16 h = __float2bfloat16(f);   // RNE
    unsigned short u;
    __builtin_memcpy(&u, &h, 2);
    return (unsigned int)u;
}
__device__ inline float bfl(unsigned int u) { return __uint_as_float(u << 16); }
__device__ inline float bfh(unsigned int u) { return __uint_as_float(u & 0xffff0000u); }

// ---------------- init: zero counters, fill perm with -1 ----------------
__global__ void init_kernel(int* __restrict__ bcnt, int* __restrict__ perm,
                            int* __restrict__ lc, int* __restrict__ lcur,
                            int permCap) {
    int i = blockIdx.x * 256 + threadIdx.x;
    if (i < 256) bcnt[i] = 0;
    if (i < permCap) perm[i] = -1;
    if (i < NT) { lc[i] = 0; lcur[i] = 0; }
}

// ---------------- label histogram (wave-aggregated atomics) ----------------
__global__ void hist_labels(const int* __restrict__ labels, int* __restrict__ lc, int N) {
    int n = blockIdx.x * 256 + threadIdx.x;
    int lab = (n < N) ? labels[n] : -1;
    int lane = threadIdx.x & 63;
    for (int l = 0; l < NT; ++l) {
        unsigned long long m = __ballot(lab == l);
        if (m == 0ull) continue;
        if (lane == __builtin_ctzll(m)) atomicAdd(&lc[l], (int)__popcll(m));
    }
}

// ---------------- label region starts (padded to 16) ----------------
__global__ void label_start_kernel(const int* __restrict__ lc, int* __restrict__ lstart) {
    if (threadIdx.x == 0 && blockIdx.x == 0) {
        int run = 0;
        for (int l = 0; l < NT; ++l) { lstart[l] = run; run += (lc[l] + 15) & ~15; }
    }
}

// ---------------- scatter nodes into label-sorted perm ----------------
__global__ void scatter_nodes(const int* __restrict__ labels, const int* __restrict__ lstart,
                              int* __restrict__ lcur, int* __restrict__ perm, int N) {
    int n = blockIdx.x * 256 + threadIdx.x;
    int lab = (n < N) ? labels[n] : -1;
    int lane = threadIdx.x & 63;
    for (int l = 0; l < NT; ++l) {
        unsigned long long m = __ballot(lab == l);
        if (m == 0ull) continue;
        int leader = __builtin_ctzll(m);
        int base = 0;
        if (lane == leader) base = atomicAdd(&lcur[l], (int)__popcll(m));
        base = __shfl(base, leader, 64);
        if (lab == l) {
            int prefix = (int)__popcll(m & ((1ull << lane) - 1ull));
            perm[lstart[l] + base + prefix] = n;
        }
    }
}

// ============ CSR build: 2-level bucket radix sort (bucket = dst>>8) ============

// Pass A: bucket histogram (LDS-aggregated)
__global__ __launch_bounds__(512) void bucket_count(const int* __restrict__ dst,
                                                    int* __restrict__ bcnt, int E) {
    __shared__ int h[256];
    int tid = threadIdx.x;
    if (tid < 256) h[tid] = 0;
    __syncthreads();
    int base = blockIdx.x * 4096;
#pragma unroll
    for (int k = 0; k < 8; ++k) {
        int e = base + k * 512 + tid;
        if (e < E) atomicAdd(&h[((unsigned)dst[e]) >> 8], 1);
    }
    __syncthreads();
    if (tid < 256) { int v = h[tid]; if (v) atomicAdd(&bcnt[tid], v); }
}

// Scan bucket counts -> boff (exclusive), init gcur, write rowoff[N]=E
__global__ __launch_bounds__(256) void bucket_scan(const int* __restrict__ bcnt,
                                                   int* __restrict__ boff, int* __restrict__ gcur,
                                                   int* __restrict__ rowoff, int NB, int N, int E) {
    __shared__ int s[256];
    int tid = threadIdx.x;
    int own = (tid < NB) ? bcnt[tid] : 0;
    s[tid] = own;
    __syncthreads();
    for (int d = 1; d < 256; d <<= 1) {
        int v = (tid >= d) ? s[tid - d] : 0;
        __syncthreads();
        s[tid] += v;
        __syncthreads();
    }
    int excl = s[tid] - own;   // exclusive prefix
    if (tid < NB) { boff[tid] = excl; gcur[tid] = excl; }
    if (tid == 0) { boff[NB] = E; rowoff[N] = E; }
}

// Pass B: scatter edges into bucket regions (block-dense appends)
__global__ __launch_bounds__(512) void bucket_scatter(
    const int* __restrict__ src, const int* __restrict__ dst, const float* __restrict__ w,
    int* __restrict__ gcur, uint2* __restrict__ earr, unsigned char* __restrict__ dlow, int E) {
    __shared__ int h[256];
    __shared__ int basearr[256];
    int tid = threadIdx.x;
    if (tid < 256) h[tid] = 0;
    __syncthreads();
    int base = blockIdx.x * 4096;
    int b[8], rank[8], sv[8], dl[8]; float wv[8];
#pragma unroll
    for (int k = 0; k < 8; ++k) {
        int e = base + k * 512 + tid;
        if (e < E) {
            int d = dst[e];
            b[k] = ((unsigned)d) >> 8;
            dl[k] = d & 255;
            sv[k] = src[e];
            wv[k] = w[e];
            rank[k] = atomicAdd(&h[b[k]], 1);
        } else b[k] = -1;
    }
    __syncthreads();
    if (tid < 256) { int c = h[tid]; basearr[tid] = c ? atomicAdd(&gcur[tid], c) : 0; }
    __syncthreads();
#pragma unroll
    for (int k = 0; k < 8; ++k) {
        if (b[k] >= 0) {
            int pos = basearr[b[k]] + rank[k];
            earr[pos] = make_uint2((unsigned)sv[k], __float_as_uint(wv[k]));
            dlow[pos] = (unsigned char)dl[k];
        }
    }
}

// Pass C: within-bucket counting sort -> final CSR edata + rowoff
__global__ __launch_bounds__(1024) void bucket_sort(
    const uint2* __restrict__ earr, const unsigned char* __restrict__ dlow,
    const int* __restrict__ boff, int* __restrict__ rowoff, uint2* __restrict__ edata, int N) {
    int b = blockIdx.x;
    int s = boff[b], e = boff[b + 1];
    __shared__ int cnt[256], off[256];
    int tid = threadIdx.x;
    if (tid < 256) cnt[tid] = 0;
    __syncthreads();
    for (int i = s + tid; i < e; i += 1024) atomicAdd(&cnt[dlow[i]], 1);
    __syncthreads();
    if (tid < 256) off[tid] = cnt[tid];
    __syncthreads();
    for (int d = 1; d < 256; d <<= 1) {
        int v = 0;
        if (tid < 256 && tid >= d) v = off[tid - d];
        __syncthreads();
        if (tid < 256) off[tid] += v;
        __syncthreads();
    }
    if (tid < 256) {
        int excl = off[tid] - cnt[tid];
        int node = b * 256 + tid;
        if (node < N) rowoff[node] = s + excl;
        off[tid] = excl;            // reuse as within-bucket cursor
    }
    __syncthreads();
    for (int i = s + tid; i < e; i += 1024) {
        int d = dlow[i];
        int r = atomicAdd(&off[d], 1);
        edata[s + r] = earr[i];
    }
}

// ---------------- cast x (fp32) -> bf16, vectorized ----------------
__global__ void cast_x(const float* __restrict__ x, unsigned short* __restrict__ xb, int total4) {
    int i = blockIdx.x * 256 + threadIdx.x;
    if (i < total4) {
        const float4* xv = (const float4*)x;
        float4 v = xv[i];
        unsigned int lo = f2bf_bits(v.x) | (f2bf_bits(v.y) << 16);
        unsigned int hi = f2bf_bits(v.z) | (f2bf_bits(v.w) << 16);
        uint2 o; o.x = lo; o.y = hi;
        ((uint2*)xb)[i] = o;
    }
}

// ---------------- cast W (fp32) -> bf16 in B-fragment swizzled layout ----------------
// Wswz index: (((lab*8 + k0)*OUTF + n)*4 + q)*8 + j ; element = W[lab][k0*32+q*8+j][n]
__global__ void cast_w(const float* __restrict__ W, unsigned short* __restrict__ Wswz,
                       int OUTF, int total) {
    int idx = blockIdx.x * 256 + threadIdx.x;
    if (idx < total) {
        int n = idx % OUTF;
        int r = idx / OUTF;          // = lab*256 + k  (k = k0*32+q*8+j)
        int j = r & 7, q = (r >> 3) & 3, k0 = (r >> 5) & 7, lab = r >> 8;
        int k = k0 * 32 + q * 8 + j;
        float f = W[((size_t)(lab * FEAT + k)) * OUTF + n];
        Wswz[((((size_t)lab * 8 + k0) * OUTF + n) * 4 + q) * 8 + j] = (unsigned short)f2bf_bits(f);
    }
}

// ---------------- projection: support = x @ W[label[node]]  (bf16 MFMA) ----------------
template <int OUTF>
__global__ __launch_bounds__(256) void proj_kernel(
    const unsigned short* __restrict__ xb, const unsigned short* __restrict__ Wswz,
    const int* __restrict__ perm, const int* __restrict__ labels,
    unsigned short* __restrict__ outp, int groups) {
    int warp = threadIdx.x >> 6;
    int lane = threadIdx.x & 63;
    int gm, n0;
    if constexpr (OUTF == 256) { gm = blockIdx.x; n0 = warp * 64; }
    else { gm = blockIdx.x * 4 + warp; n0 = 0; if (gm >= groups) return; }
    int m0 = gm * 16;
    int first = perm[m0];
    if (first < 0) return;                    // all-pad group
    int lab = labels[first];                  // uniform within group by construction
    int q = lane >> 4, c = lane & 15;
    int nodeA = perm[m0 + c];
    int ndA = (nodeA < 0) ? first : nodeA;    // pad rows: load a valid row, never stored

    const bf16x8* aptr = (const bf16x8*)(xb + (size_t)ndA * FEAT + q * 8);
    const unsigned short* bb = Wswz + (size_t)lab * FEAT * OUTF + (size_t)(n0 + c) * 32 + q * 8;

    f32x4 acc[4] = {};
#pragma unroll
    for (int k0 = 0; k0 < 8; ++k0) {
        bf16x8 a = aptr[k0 * 4];
        const unsigned short* bk = bb + (size_t)k0 * 32 * OUTF;
#pragma unroll
        for (int t = 0; t < 4; ++t) {
            bf16x8 b = *(const bf16x8*)(bk + t * 512);
            acc[t] = __builtin_amdgcn_mfma_f32_16x16x32_bf16(a, b, acc[t], 0, 0, 0);
        }
    }
    // C/D layout: row=(lane>>4)*4+reg, col=lane&15
    __hip_bfloat16* ob = (__hip_bfloat16*)outp;
#pragma unroll
    for (int r = 0; r < 4; ++r) {
        int noder = perm[m0 + q * 4 + r];
        if (noder >= 0) {
#pragma unroll
            for (int t = 0; t < 4; ++t)
                ob[(size_t)noder * OUTF + n0 + t * 16 + c] = __float2bfloat16(acc[t][r]);
        }
    }
}

// ---------------- aggregation, 256-feat: one wave per node, scalar edge loads ----------
// node is wave-uniform (readfirstlane) -> edge records load as s_load; gather address is
// sgpr_base + lane offset. lane holds feats [4*lane, 4*lane+4) as uint2 (4 bf16).
__global__ __launch_bounds__(256) void agg256_kernel(
    const uint2* __restrict__ sup, const int* __restrict__ rowoff,
    const uint2* __restrict__ edata, const float* __restrict__ bias,
    uint2* __restrict__ outp, int N) {
    int warp = __builtin_amdgcn_readfirstlane((int)(threadIdx.x >> 6));
    int node = (int)blockIdx.x * 4 + warp;
    if (node >= N) return;
    int lane = threadIdx.x & 63;
    int s = rowoff[node], e = rowoff[node + 1];
    float a0 = 0.f, a1 = 0.f, a2 = 0.f, a3 = 0.f;
    int j = s;
    for (; j + 4 <= e; j += 4) {
        uint2 e0 = edata[j + 0], e1 = edata[j + 1], e2 = edata[j + 2], e3 = edata[j + 3];
        uint2 v0 = sup[(size_t)e0.x * 64 + lane];
        uint2 v1 = sup[(size_t)e1.x * 64 + lane];
        uint2 v2 = sup[(size_t)e2.x * 64 + lane];
        uint2 v3 = sup[(size_t)e3.x * 64 + lane];
        float w0 = __uint_as_float(e0.y), w1 = __uint_as_float(e1.y);
        float w2 = __uint_as_float(e2.y), w3 = __uint_as_float(e3.y);
        a0 += w0 * bfl(v0.x); a1 += w0 * bfh(v0.x); a2 += w0 * bfl(v0.y); a3 += w0 * bfh(v0.y);
        a0 += w1 * bfl(v1.x); a1 += w1 * bfh(v1.x); a2 += w1 * bfl(v1.y); a3 += w1 * bfh(v1.y);
        a0 += w2 * bfl(v2.x); a1 += w2 * bfh(v2.x); a2 += w2 * bfl(v2.y); a3 += w2 * bfh(v2.y);
        a0 += w3 * bfl(v3.x); a1 += w3 * bfh(v3.x); a2 += w3 * bfl(v3.y); a3 += w3 * bfh(v3.y);
    }
    for (; j < e; ++j) {
        uint2 ed = edata[j];
        uint2 v = sup[(size_t)ed.x * 64 + lane];
        float w = __uint_as_float(ed.y);
        a0 += w * bfl(v.x); a1 += w * bfh(v.x); a2 += w * bfl(v.y); a3 += w * bfh(v.y);
    }
    float4 b = ((const float4*)bias)[lane];
    a0 = fmaxf(a0 + b.x, 0.f);
    a1 = fmaxf(a1 + b.y, 0.f);
    a2 = fmaxf(a2 + b.z, 0.f);
    a3 = fmaxf(a3 + b.w, 0.f);
    unsigned int lo = f2bf_bits(a0) | (f2bf_bits(a1) << 16);
    unsigned int hi = f2bf_bits(a2) | (f2bf_bits(a3) << 16);
    outp[(size_t)node * 64 + lane] = make_uint2(lo, hi);
}

// ---------------- aggregation, 64-feat: one wave per node (lane = feat), fp32 out ------
__global__ __launch_bounds__(256) void agg64_kernel(
    const unsigned short* __restrict__ sup, const int* __restrict__ rowoff,
    const uint2* __restrict__ edata, const float* __restrict__ bias,
    float* __restrict__ outp, int N) {
    int warp = __builtin_amdgcn_readfirstlane((int)(threadIdx.x >> 6));
    int node = (int)blockIdx.x * 4 + warp;
    if (node >= N) return;
    int lane = threadIdx.x & 63;
    int s = rowoff[node], e = rowoff[node + 1];
    float a = 0.f;
    int j = s;
    for (; j + 4 <= e; j += 4) {
        uint2 e0 = edata[j + 0], e1 = edata[j + 1], e2 = edata[j + 2], e3 = edata[j + 3];
        unsigned short v0 = sup[(size_t)e0.x * 64 + lane];
        unsigned short v1 = sup[(size_t)e1.x * 64 + lane];
        unsigned short v2 = sup[(size_t)e2.x * 64 + lane];
        unsigned short v3 = sup[(size_t)e3.x * 64 + lane];
        a += __uint_as_float(e0.y) * __uint_as_float((unsigned int)v0 << 16);
        a += __uint_as_float(e1.y) * __uint_as_float((unsigned int)v1 << 16);
        a += __uint_as_float(e2.y) * __uint_as_float((unsigned int)v2 << 16);
        a += __uint_as_float(e3.y) * __uint_as_float((unsigned int)v3 << 16);
    }
    for (; j < e; ++j) {
        uint2 ed = edata[j];
        unsigned short v = sup[(size_t)ed.x * 64 + lane];
        a += __uint_as_float(ed.y) * __uint_as_float((unsigned int)v << 16);
    }
    a += bias[lane];
    outp[(size_t)node * 64 + lane] = a;
}

extern "C" void kernel_launch(void* const* d_in, const int* in_sizes, int n_in,
                              void* d_out, int out_size, void* d_ws, size_t ws_size,
                              hipStream_t stream) {
    const float* x        = (const float*)d_in[0];
    const int*   edge_src = (const int*)d_in[1];
    const int*   edge_dst = (const int*)d_in[2];
    const float* edge_w   = (const float*)d_in[3];
    const int*   labels   = (const int*)d_in[4];
    const float* W1 = (const float*)d_in[5];
    const float* b1 = (const float*)d_in[6];
    const float* W2 = (const float*)d_in[7];
    const float* b2 = (const float*)d_in[8];
    const float* W3 = (const float*)d_in[9];
    const float* b3 = (const float*)d_in[10];

    const int N = in_sizes[0] / FEAT;
    const int E = in_sizes[1];
    const int NB = (N + 255) >> 8;                 // dst buckets (<=256 for N<=65536)
    const int groups  = (N + NT * 16 + 15) / 16;   // 16-node tiles incl. per-label padding
    const int permCap = groups * 16;

    // ---- workspace carve (256B aligned) ----
    char* p = (char*)d_ws;
    auto alloc = [&](size_t bytes) -> char* {
        char* r = p;
        p += (bytes + 255) & ~(size_t)255;
        return r;
    };
    unsigned short* bufA = (unsigned short*)alloc((size_t)N * FEAT * 2);
    unsigned short* bufB = (unsigned short*)alloc((size_t)N * FEAT * 2);
    unsigned short* W1b  = (unsigned short*)alloc((size_t)NT * FEAT * FEAT * 2);
    unsigned short* W2b  = (unsigned short*)alloc((size_t)NT * FEAT * FEAT * 2);
    unsigned short* W3b  = (unsigned short*)alloc((size_t)NT * FEAT * OUT3 * 2);
    int*   rowoff = (int*)alloc((size_t)(N + 1) * 4);
    uint2* edata  = (uint2*)alloc((size_t)E * 8);
    int*   perm   = (int*)alloc((size_t)permCap * 4);
    int*   bcnt   = (int*)alloc(256 * 4);
    int*   boff   = (int*)alloc(257 * 4);
    int*   gcur   = (int*)alloc(256 * 4);
    int*   lc     = (int*)alloc(64);
    int*   lcur   = (int*)alloc(64);
    int*   lstart = (int*)alloc(64);
    // staging for bucket sort ALIASED onto bufA (consumed before cast_x writes bufA)
    uint2*         earr = (uint2*)bufA;                       // E*8 bytes
    unsigned char* dlow = (unsigned char*)bufA + (size_t)E * 8; // E bytes  (14.4MB <= 25.6MB)

    const int nbEB = (E + 4095) / 4096;

    // ---- CSR build (bucket radix) + label-sort ----
    init_kernel<<<(permCap + 255) / 256, 256, 0, stream>>>(bcnt, perm, lc, lcur, permCap);
    hist_labels<<<(N + 255) / 256, 256, 0, stream>>>(labels, lc, N);
    bucket_count<<<nbEB, 512, 0, stream>>>(edge_dst, bcnt, E);
    bucket_scan<<<1, 256, 0, stream>>>(bcnt, boff, gcur, rowoff, NB, N, E);
    label_start_kernel<<<1, 64, 0, stream>>>(lc, lstart);
    scatter_nodes<<<(N + 255) / 256, 256, 0, stream>>>(labels, lstart, lcur, perm, N);
    bucket_scatter<<<nbEB, 512, 0, stream>>>(edge_src, edge_dst, edge_w, gcur, earr, dlow, E);
    bucket_sort<<<NB, 1024, 0, stream>>>(earr, dlow, boff, rowoff, edata, N);

    // ---- casts (cast_x overwrites bufA AFTER bucket_sort consumed earr/dlow) ----
    cast_x<<<((N * FEAT / 4) + 255) / 256, 256, 0, stream>>>(x, bufA, N * FEAT / 4);
    cast_w<<<((NT * FEAT * FEAT) + 255) / 256, 256, 0, stream>>>(W1, W1b, FEAT, NT * FEAT * FEAT);
    cast_w<<<((NT * FEAT * FEAT) + 255) / 256, 256, 0, stream>>>(W2, W2b, FEAT, NT * FEAT * FEAT);
    cast_w<<<((NT * FEAT * OUT3) + 255) / 256, 256, 0, stream>>>(W3, W3b, OUT3, NT * FEAT * OUT3);

    // ---- layer 1 ----
    proj_kernel<256><<<groups, 256, 0, stream>>>(bufA, W1b, perm, labels, bufB, groups);
    agg256_kernel<<<(N + 3) / 4, 256, 0, stream>>>((const uint2*)bufB, rowoff, edata, b1, (uint2*)bufA, N);
    // ---- layer 2 ----
    proj_kernel<256><<<groups, 256, 0, stream>>>(bufA, W2b, perm, labels, bufB, groups);
    agg256_kernel<<<(N + 3) / 4, 256, 0, stream>>>((const uint2*)bufB, rowoff, edata, b2, (uint2*)bufA, N);
    // ---- layer 3 ----
    proj_kernel<64><<<(groups + 3) / 4, 256, 0, stream>>>(bufA, W3b, perm, labels, bufB, groups);
    agg64_kernel<<<(N + 3) / 4, 256, 0, stream>>>(bufB, rowoff, edata, b3, (float*)d_out, N);
}

// Round 4
// 509.985 us; speedup vs baseline: 2.3549x; 1.1683x over previous
//
#include <hip/hip_runtime.h>
#include <hip/hip_bf16.h>

#define NT 4           // node types (labels)
#define FEAT 256       // nfeat == nhid
#define OUT3 64        // nclass

typedef __bf16 bf16x8 __attribute__((ext_vector_type(8)));
typedef float  f32x4  __attribute__((ext_vector_type(4)));

__device__ inline unsigned int f2bf_bits(float f) {
    __hip_bfloat16 h = __float2bfloat16(f);   // RNE
    unsigned short u;
    __builtin_memcpy(&u, &h, 2);
    return (unsigned int)u;
}
__device__ inline float bfl(unsigned int u) { return __uint_as_float(u << 16); }
__device__ inline float bfh(unsigned int u) { return __uint_as_float(u & 0xffff0000u); }

// ---------------- zero small counters ----------------
__global__ void zero_small(int* __restrict__ bcnt, int* __restrict__ lc, int* __restrict__ lcur) {
    int i = threadIdx.x;
    bcnt[i] = 0;
    if (i < NT) { lc[i] = 0; lcur[i] = 0; }
}

// ---------------- pass A: bucket histogram (dst>>8) + label histogram ----------------
__global__ __launch_bounds__(512) void bucket_count(const int* __restrict__ dst,
                                                    const int* __restrict__ labels,
                                                    int* __restrict__ bcnt, int* __restrict__ lc,
                                                    int E, int N) {
    __shared__ int h[256];
    __shared__ int lh[NT];
    int tid = threadIdx.x;
    if (tid < 256) h[tid] = 0;
    if (tid < NT) lh[tid] = 0;
    __syncthreads();
    int base = blockIdx.x * 4096;
#pragma unroll
    for (int k = 0; k < 8; ++k) {
        int e = base + k * 512 + tid;
        if (e < E) atomicAdd(&h[((unsigned)dst[e]) >> 8], 1);
    }
#pragma unroll
    for (int k = 0; k < 8; ++k) {
        int i = base + k * 512 + tid;
        if (i < N) atomicAdd(&lh[labels[i]], 1);
    }
    __syncthreads();
    if (tid < 256) { int v = h[tid]; if (v) atomicAdd(&bcnt[tid], v); }
    if (tid < NT) { int v = lh[tid]; if (v) atomicAdd(&lc[tid], v); }
}

// ------- scan buckets -> boff/gcur, rowoff[N]=E; label starts (pad 64) + perm pads -------
__global__ __launch_bounds__(256) void scan_master(
    const int* __restrict__ bcnt, const int* __restrict__ lc,
    int* __restrict__ boff, int* __restrict__ gcur, int* __restrict__ rowoff,
    int* __restrict__ lstart, int* __restrict__ perm,
    int NB, int N, int E, int permCap) {
    __shared__ int s[256];
    int tid = threadIdx.x;
    int own = (tid < NB) ? bcnt[tid] : 0;
    s[tid] = own;
    __syncthreads();
    for (int d = 1; d < 256; d <<= 1) {
        int v = (tid >= d) ? s[tid - d] : 0;
        __syncthreads();
        s[tid] += v;
        __syncthreads();
    }
    int excl = s[tid] - own;
    if (tid < NB) { boff[tid] = excl; gcur[tid] = excl; }
    if (tid == 0) {
        boff[NB] = E; rowoff[N] = E;
        int run = 0;
        int ls[NT], cnt[NT];
        for (int l = 0; l < NT; ++l) {
            ls[l] = run; cnt[l] = lc[l];
            lstart[l] = run;
            run += (cnt[l] + 63) & ~63;
        }
        for (int l = 0; l < NT; ++l) {
            int end = (l + 1 < NT) ? ls[l + 1] : run;
            for (int i = ls[l] + cnt[l]; i < end; ++i) perm[i] = -1;
        }
        for (int i = run; i < permCap; ++i) perm[i] = -1;
    }
}

// ------- pass B (edges) + node scatter, combined grid -------
// edge record: x = src | (dst&255)<<16 ; y = w fp32
__global__ __launch_bounds__(512) void scatter_combined(
    const int* __restrict__ src, const int* __restrict__ dst, const float* __restrict__ w,
    int* __restrict__ gcur, uint2* __restrict__ earr, int E, int nbEB,
    const int* __restrict__ labels, const int* __restrict__ lstart,
    int* __restrict__ lcur, int* __restrict__ perm, int N) {
    int tid = threadIdx.x;
    if ((int)blockIdx.x < nbEB) {
        __shared__ int h[256];
        __shared__ int basearr[256];
        if (tid < 256) h[tid] = 0;
        __syncthreads();
        int base = blockIdx.x * 4096;
        int b[8], rank[8], px[8]; float wv[8];
#pragma unroll
        for (int k = 0; k < 8; ++k) {
            int e = base + k * 512 + tid;
            if (e < E) {
                int d = dst[e];
                b[k] = ((unsigned)d) >> 8;
                px[k] = src[e] | ((d & 255) << 16);
                wv[k] = w[e];
                rank[k] = atomicAdd(&h[b[k]], 1);
            } else b[k] = -1;
        }
        __syncthreads();
        if (tid < 256) { int c = h[tid]; basearr[tid] = c ? atomicAdd(&gcur[tid], c) : 0; }
        __syncthreads();
#pragma unroll
        for (int k = 0; k < 8; ++k) {
            if (b[k] >= 0) {
                int pos = basearr[b[k]] + rank[k];
                earr[pos] = make_uint2((unsigned)px[k], __float_as_uint(wv[k]));
            }
        }
    } else {
        int n = ((int)blockIdx.x - nbEB) * 512 + tid;
        int lab = (n < N) ? labels[n] : -1;
        int lane = tid & 63;
        for (int l = 0; l < NT; ++l) {
            unsigned long long m = __ballot(lab == l);
            if (m == 0ull) continue;
            int leader = __builtin_ctzll(m);
            int base = 0;
            if (lane == leader) base = atomicAdd(&lcur[l], (int)__popcll(m));
            base = __shfl(base, leader, 64);
            if (lab == l) {
                int prefix = (int)__popcll(m & ((1ull << lane) - 1ull));
                perm[lstart[l] + base + prefix] = n;
            }
        }
    }
}

// ------- pass C: within-bucket counting sort -> rowoff + final 4B edge records -------
// final record: (w_bf16 << 16) | src
__global__ __launch_bounds__(1024) void bucket_sort(
    const uint2* __restrict__ earr, const int* __restrict__ boff,
    int* __restrict__ rowoff, unsigned int* __restrict__ edata, int N) {
    int b = blockIdx.x;
    int s = boff[b], e = boff[b + 1];
    __shared__ int cnt[256], off[256];
    int tid = threadIdx.x;
    if (tid < 256) cnt[tid] = 0;
    __syncthreads();
    for (int i = s + tid; i < e; i += 1024) atomicAdd(&cnt[(earr[i].x >> 16) & 255], 1);
    __syncthreads();
    if (tid < 256) off[tid] = cnt[tid];
    __syncthreads();
    for (int d = 1; d < 256; d <<= 1) {
        int v = 0;
        if (tid < 256 && tid >= d) v = off[tid - d];
        __syncthreads();
        if (tid < 256) off[tid] += v;
        __syncthreads();
    }
    if (tid < 256) {
        int excl = off[tid] - cnt[tid];
        int node = b * 256 + tid;
        if (node < N) rowoff[node] = s + excl;
        off[tid] = excl;
    }
    __syncthreads();
    for (int i = s + tid; i < e; i += 1024) {
        uint2 r = earr[i];
        int d = (r.x >> 16) & 255;
        int k = atomicAdd(&off[d], 1);
        edata[s + k] = (f2bf_bits(__uint_as_float(r.y)) << 16) | (r.x & 0xffff);
    }
}

// ---------------- cast x (fp32) -> bf16, vectorized ----------------
__global__ void cast_x(const float* __restrict__ x, unsigned short* __restrict__ xb, int total4) {
    int i = blockIdx.x * 256 + threadIdx.x;
    if (i < total4) {
        const float4* xv = (const float4*)x;
        float4 v = xv[i];
        unsigned int lo = f2bf_bits(v.x) | (f2bf_bits(v.y) << 16);
        unsigned int hi = f2bf_bits(v.z) | (f2bf_bits(v.w) << 16);
        uint2 o; o.x = lo; o.y = hi;
        ((uint2*)xb)[i] = o;
    }
}

// ---------------- cast all W (fp32) -> bf16 B-fragment swizzled, one launch ----------------
// Wswz linear index: (lab*FEAT + k0*32)*OUTF + n*32 + q*8 + j ; element = W[lab][k0*32+q*8+j][n]
__global__ void cast_w_all(const float* __restrict__ W1, const float* __restrict__ W2,
                           const float* __restrict__ W3, unsigned short* __restrict__ W1b,
                           unsigned short* __restrict__ W2b, unsigned short* __restrict__ W3b) {
    const int S = NT * FEAT * FEAT;
    int idx = blockIdx.x * 256 + threadIdx.x;
    const float* W; unsigned short* D; int OUTF; int t;
    if (idx < S)            { W = W1; D = W1b; OUTF = FEAT; t = idx; }
    else if (idx < 2 * S)   { W = W2; D = W2b; OUTF = FEAT; t = idx - S; }
    else if (idx < 2 * S + NT * FEAT * OUT3) { W = W3; D = W3b; OUTF = OUT3; t = idx - 2 * S; }
    else return;
    int n = t % OUTF;
    int r = t / OUTF;              // lab*256 + k
    int j = r & 7, q = (r >> 3) & 3, k0 = (r >> 5) & 7, lab = r >> 8;
    int k = k0 * 32 + q * 8 + j;
    float f = W[((size_t)(lab * FEAT + k)) * OUTF + n];
    D[(((size_t)lab * 8 + k0) * OUTF + n) * 32 + q * 8 + j] = (unsigned short)f2bf_bits(f);
}

// ---------------- proj 256-out: 64 nodes x 256 outs per block ----------------
// warp w: all 4 m-subtiles x 4 n-tiles at n0 = w*64. 16 MFMA per 8 loads per k0 step.
__global__ __launch_bounds__(256) void proj256_kernel(
    const unsigned short* __restrict__ xb, const unsigned short* __restrict__ Wswz,
    const int* __restrict__ perm, const int* __restrict__ labels,
    unsigned short* __restrict__ outp) {
    int warp = threadIdx.x >> 6;
    int lane = threadIdx.x & 63;
    int m0 = blockIdx.x * 64;
    int first = perm[m0];
    if (first < 0) return;                    // all-pad group
    int lab = labels[first];
    int q = lane >> 4, c = lane & 15;
    int n0 = warp * 64;

    const unsigned short* arow[4];
#pragma unroll
    for (int t = 0; t < 4; ++t) {
        int nd = perm[m0 + t * 16 + c];
        arow[t] = xb + (size_t)((nd < 0) ? first : nd) * FEAT;
    }
    const unsigned short* bb = Wswz + (size_t)lab * FEAT * 256 + (size_t)(n0 + c) * 32 + q * 8;

    f32x4 acc[4][4] = {};
#pragma unroll
    for (int k0 = 0; k0 < 8; ++k0) {
        bf16x8 a[4];
#pragma unroll
        for (int t = 0; t < 4; ++t) a[t] = *(const bf16x8*)(arow[t] + k0 * 32 + q * 8);
        const unsigned short* bk = bb + (size_t)k0 * 32 * 256;
#pragma unroll
        for (int u = 0; u < 4; ++u) {
            bf16x8 bfrag = *(const bf16x8*)(bk + u * 512);
#pragma unroll
            for (int t = 0; t < 4; ++t)
                acc[t][u] = __builtin_amdgcn_mfma_f32_16x16x32_bf16(a[t], bfrag, acc[t][u], 0, 0, 0);
        }
    }
    __hip_bfloat16* ob = (__hip_bfloat16*)outp;
#pragma unroll
    for (int t = 0; t < 4; ++t) {
#pragma unroll
        for (int r = 0; r < 4; ++r) {
            int noder = perm[m0 + t * 16 + q * 4 + r];
            if (noder >= 0) {
#pragma unroll
                for (int u = 0; u < 4; ++u)
                    ob[(size_t)noder * 256 + n0 + u * 16 + c] = __float2bfloat16(acc[t][u][r]);
            }
        }
    }
}

// ---------------- proj 64-out: 64 nodes x 64 outs per block (warp = m-subtile) ----------
__global__ __launch_bounds__(256) void proj64_kernel(
    const unsigned short* __restrict__ xb, const unsigned short* __restrict__ Wswz,
    const int* __restrict__ perm, const int* __restrict__ labels,
    unsigned short* __restrict__ outp) {
    int warp = threadIdx.x >> 6;
    int lane = threadIdx.x & 63;
    int m0 = blockIdx.x * 64;
    int first = perm[m0];
    if (first < 0) return;
    int lab = labels[first];
    int q = lane >> 4, c = lane & 15;
    int mb = m0 + warp * 16;

    int ndc = perm[mb + c];
    const unsigned short* arow = xb + (size_t)((ndc < 0) ? first : ndc) * FEAT;
    const unsigned short* bb = Wswz + (size_t)lab * FEAT * OUT3 + (size_t)c * 32 + q * 8;

    f32x4 acc[4] = {};
#pragma unroll
    for (int k0 = 0; k0 < 8; ++k0) {
        bf16x8 a = *(const bf16x8*)(arow + k0 * 32 + q * 8);
        const unsigned short* bk = bb + (size_t)k0 * 32 * OUT3;
#pragma unroll
        for (int u = 0; u < 4; ++u) {
            bf16x8 bfrag = *(const bf16x8*)(bk + u * 512);
            acc[u] = __builtin_amdgcn_mfma_f32_16x16x32_bf16(a, bfrag, acc[u], 0, 0, 0);
        }
    }
    __hip_bfloat16* ob = (__hip_bfloat16*)outp;
#pragma unroll
    for (int r = 0; r < 4; ++r) {
        int noder = perm[mb + q * 4 + r];
        if (noder >= 0) {
#pragma unroll
            for (int u = 0; u < 4; ++u)
                ob[(size_t)noder * OUT3 + u * 16 + c] = __float2bfloat16(acc[u][r]);
        }
    }
}

// ---------------- aggregation, 256-feat: one wave per node, unroll 8 ----------------
// edge record: (w_bf16<<16) | src.  lane holds feats [4*lane,4*lane+4) as uint2.
__global__ __launch_bounds__(256) void agg256_kernel(
    const uint2* __restrict__ sup, const int* __restrict__ rowoff,
    const unsigned int* __restrict__ edata, const float* __restrict__ bias,
    uint2* __restrict__ outp, int N) {
    int warp = __builtin_amdgcn_readfirstlane((int)(threadIdx.x >> 6));
    int node = (int)blockIdx.x * 4 + warp;
    if (node >= N) return;
    int lane = threadIdx.x & 63;
    int s = __builtin_amdgcn_readfirstlane(rowoff[node]);
    int e = __builtin_amdgcn_readfirstlane(rowoff[node + 1]);
    float a0 = 0.f, a1 = 0.f, a2 = 0.f, a3 = 0.f;
    int j = s;
    for (; j + 8 <= e; j += 8) {
        int ed[8]; uint2 v[8];
#pragma unroll
        for (int u = 0; u < 8; ++u) ed[u] = __builtin_amdgcn_readfirstlane((int)edata[j + u]);
#pragma unroll
        for (int u = 0; u < 8; ++u) v[u] = sup[(size_t)(ed[u] & 0xffff) * 64 + lane];
#pragma unroll
        for (int u = 0; u < 8; ++u) {
            float w = __uint_as_float((unsigned int)ed[u] & 0xffff0000u);
            a0 += w * bfl(v[u].x); a1 += w * bfh(v[u].x);
            a2 += w * bfl(v[u].y); a3 += w * bfh(v[u].y);
        }
    }
    if (j < e) {   // masked tail (≤7 real edges)
        int ed[8]; float wm[8]; uint2 v[8];
#pragma unroll
        for (int u = 0; u < 8; ++u) {
            int jj = j + u;
            int jc = (jj < e) ? jj : e - 1;
            ed[u] = __builtin_amdgcn_readfirstlane((int)edata[jc]);
            wm[u] = (jj < e) ? __uint_as_float((unsigned int)ed[u] & 0xffff0000u) : 0.f;
        }
#pragma unroll
        for (int u = 0; u < 8; ++u) v[u] = sup[(size_t)(ed[u] & 0xffff) * 64 + lane];
#pragma unroll
        for (int u = 0; u < 8; ++u) {
            a0 += wm[u] * bfl(v[u].x); a1 += wm[u] * bfh(v[u].x);
            a2 += wm[u] * bfl(v[u].y); a3 += wm[u] * bfh(v[u].y);
        }
    }
    float4 b = ((const float4*)bias)[lane];
    a0 = fmaxf(a0 + b.x, 0.f);
    a1 = fmaxf(a1 + b.y, 0.f);
    a2 = fmaxf(a2 + b.z, 0.f);
    a3 = fmaxf(a3 + b.w, 0.f);
    unsigned int lo = f2bf_bits(a0) | (f2bf_bits(a1) << 16);
    unsigned int hi = f2bf_bits(a2) | (f2bf_bits(a3) << 16);
    outp[(size_t)node * 64 + lane] = make_uint2(lo, hi);
}

// ---------------- aggregation, 64-feat: one wave per node (lane = feat), fp32 out ------
__global__ __launch_bounds__(256) void agg64_kernel(
    const unsigned short* __restrict__ sup, const int* __restrict__ rowoff,
    const unsigned int* __restrict__ edata, const float* __restrict__ bias,
    float* __restrict__ outp, int N) {
    int warp = __builtin_amdgcn_readfirstlane((int)(threadIdx.x >> 6));
    int node = (int)blockIdx.x * 4 + warp;
    if (node >= N) return;
    int lane = threadIdx.x & 63;
    int s = __builtin_amdgcn_readfirstlane(rowoff[node]);
    int e = __builtin_amdgcn_readfirstlane(rowoff[node + 1]);
    float a = 0.f;
    int j = s;
    for (; j + 8 <= e; j += 8) {
        int ed[8]; unsigned short v[8];
#pragma unroll
        for (int u = 0; u < 8; ++u) ed[u] = __builtin_amdgcn_readfirstlane((int)edata[j + u]);
#pragma unroll
        for (int u = 0; u < 8; ++u) v[u] = sup[(size_t)(ed[u] & 0xffff) * 64 + lane];
#pragma unroll
        for (int u = 0; u < 8; ++u)
            a += __uint_as_float((unsigned int)ed[u] & 0xffff0000u) * __uint_as_float((unsigned int)v[u] << 16);
    }
    if (j < e) {
        int ed[8]; float wm[8]; unsigned short v[8];
#pragma unroll
        for (int u = 0; u < 8; ++u) {
            int jj = j + u;
            int jc = (jj < e) ? jj : e - 1;
            ed[u] = __builtin_amdgcn_readfirstlane((int)edata[jc]);
            wm[u] = (jj < e) ? __uint_as_float((unsigned int)ed[u] & 0xffff0000u) : 0.f;
        }
#pragma unroll
        for (int u = 0; u < 8; ++u) v[u] = sup[(size_t)(ed[u] & 0xffff) * 64 + lane];
#pragma unroll
        for (int u = 0; u < 8; ++u)
            a += wm[u] * __uint_as_float((unsigned int)v[u] << 16);
    }
    a += bias[lane];
    outp[(size_t)node * 64 + lane] = a;
}

extern "C" void kernel_launch(void* const* d_in, const int* in_sizes, int n_in,
                              void* d_out, int out_size, void* d_ws, size_t ws_size,
                              hipStream_t stream) {
    const float* x        = (const float*)d_in[0];
    const int*   edge_src = (const int*)d_in[1];
    const int*   edge_dst = (const int*)d_in[2];
    const float* edge_w   = (const float*)d_in[3];
    const int*   labels   = (const int*)d_in[4];
    const float* W1 = (const float*)d_in[5];
    const float* b1 = (const float*)d_in[6];
    const float* W2 = (const float*)d_in[7];
    const float* b2 = (const float*)d_in[8];
    const float* W3 = (const float*)d_in[9];
    const float* b3 = (const float*)d_in[10];

    const int N = in_sizes[0] / FEAT;
    const int E = in_sizes[1];
    const int NB = (N + 255) >> 8;                    // dst buckets
    const int G64 = (N + NT * 64 + 63) / 64;          // 64-node groups incl. padding
    const int permCap = G64 * 64;

    // ---- workspace carve (256B aligned) ----
    char* p = (char*)d_ws;
    auto alloc = [&](size_t bytes) -> char* {
        char* r = p;
        p += (bytes + 255) & ~(size_t)255;
        return r;
    };
    unsigned short* bufA = (unsigned short*)alloc((size_t)N * FEAT * 2);
    unsigned short* bufB = (unsigned short*)alloc((size_t)N * FEAT * 2);
    unsigned short* W1b  = (unsigned short*)alloc((size_t)NT * FEAT * FEAT * 2);
    unsigned short* W2b  = (unsigned short*)alloc((size_t)NT * FEAT * FEAT * 2);
    unsigned short* W3b  = (unsigned short*)alloc((size_t)NT * FEAT * OUT3 * 2);
    int*          rowoff = (int*)alloc((size_t)(N + 1) * 4);
    unsigned int* edata  = (unsigned int*)alloc((size_t)E * 4);
    int*          perm   = (int*)alloc((size_t)permCap * 4);
    int*          bcnt   = (int*)alloc(256 * 4);
    int*          boff   = (int*)alloc(257 * 4);
    int*          gcur   = (int*)alloc(256 * 4);
    int*          lc     = (int*)alloc(64);
    int*          lcur   = (int*)alloc(64);
    int*          lstart = (int*)alloc(64);
    // bucket-sort staging ALIASED onto bufA (consumed before cast_x writes bufA)
    uint2* earr = (uint2*)bufA;   // E*8 = 12.8MB <= 25.6MB

    const int nbEB = (E + 4095) / 4096;
    const int nbN  = (N + 511) / 512;

    // ---- CSR build (bucket radix, 4B records) + label-sort ----
    zero_small<<<1, 256, 0, stream>>>(bcnt, lc, lcur);
    bucket_count<<<nbEB, 512, 0, stream>>>(edge_dst, labels, bcnt, lc, E, N);
    scan_master<<<1, 256, 0, stream>>>(bcnt, lc, boff, gcur, rowoff, lstart, perm, NB, N, E, permCap);
    scatter_combined<<<nbEB + nbN, 512, 0, stream>>>(edge_src, edge_dst, edge_w, gcur, earr, E, nbEB,
                                                     labels, lstart, lcur, perm, N);
    bucket_sort<<<NB, 1024, 0, stream>>>(earr, boff, rowoff, edata, N);

    // ---- casts (cast_x overwrites bufA AFTER bucket_sort consumed earr) ----
    cast_x<<<((N * FEAT / 4) + 255) / 256, 256, 0, stream>>>(x, bufA, N * FEAT / 4);
    {
        int totalW = 2 * NT * FEAT * FEAT + NT * FEAT * OUT3;
        cast_w_all<<<(totalW + 255) / 256, 256, 0, stream>>>(W1, W2, W3, W1b, W2b, W3b);
    }

    // ---- layer 1 ----
    proj256_kernel<<<G64, 256, 0, stream>>>(bufA, W1b, perm, labels, bufB);
    agg256_kernel<<<(N + 3) / 4, 256, 0, stream>>>((const uint2*)bufB, rowoff, edata, b1, (uint2*)bufA, N);
    // ---- layer 2 ----
    proj256_kernel<<<G64, 256, 0, stream>>>(bufA, W2b, perm, labels, bufB);
    agg256_kernel<<<(N + 3) / 4, 256, 0, stream>>>((const uint2*)bufB, rowoff, edata, b2, (uint2*)bufA, N);
    // ---- layer 3 ----
    proj64_kernel<<<G64, 256, 0, stream>>>(bufA, W3b, perm, labels, bufB);
    agg64_kernel<<<(N + 3) / 4, 256, 0, stream>>>(bufB, rowoff, edata, b3, (float*)d_out, N);
}

// Round 5
// 506.209 us; speedup vs baseline: 2.3725x; 1.0075x over previous
//
#include <hip/hip_runtime.h>
#include <hip/hip_bf16.h>

#define NT 4           // node types (labels)
#define FEAT 256       // nfeat == nhid
#define OUT3 64        // nclass

typedef __bf16 bf16x8 __attribute__((ext_vector_type(8)));
typedef float  f32x4  __attribute__((ext_vector_type(4)));

__device__ inline unsigned int f2bf_bits(float f) {
    __hip_bfloat16 h = __float2bfloat16(f);   // RNE
    unsigned short u;
    __builtin_memcpy(&u, &h, 2);
    return (unsigned int)u;
}
__device__ inline float bfl(unsigned int u) { return __uint_as_float(u << 16); }
__device__ inline float bfh(unsigned int u) { return __uint_as_float(u & 0xffff0000u); }
// stored feature pos p (pi order) -> natural feature index, within each 64-block
__device__ __host__ inline int nat_of(int p) {
    int lo = p & 63;
    return (p & ~63) | (((lo & 3) << 4) | (lo >> 2));
}

// ---------------- zero small counters ----------------
__global__ void zero_small(int* __restrict__ bcnt, int* __restrict__ lc, int* __restrict__ lcur) {
    int i = threadIdx.x;
    bcnt[i] = 0;
    if (i < NT) { lc[i] = 0; lcur[i] = 0; }
}

// ---------------- pass A: dst-bucket histogram (dst>>8) + label histogram ----------------
__global__ __launch_bounds__(512) void pass_a(const int* __restrict__ dst,
                                              const int* __restrict__ labels,
                                              int* __restrict__ bcnt, int* __restrict__ lc,
                                              int E, int N) {
    __shared__ int h[256];
    __shared__ int lh[NT];
    int tid = threadIdx.x;
    if (tid < 256) h[tid] = 0;
    if (tid < NT) lh[tid] = 0;
    __syncthreads();
    int base = blockIdx.x * 4096;
#pragma unroll
    for (int k = 0; k < 8; ++k) {
        int e = base + k * 512 + tid;
        if (e < E) atomicAdd(&h[((unsigned)dst[e]) >> 8], 1);
    }
#pragma unroll
    for (int k = 0; k < 8; ++k) {
        int i = base + k * 512 + tid;
        if (i < N) atomicAdd(&lh[labels[i]], 1);
    }
    __syncthreads();
    if (tid < 256) { int v = h[tid]; if (v) atomicAdd(&bcnt[tid], v); }
    if (tid < NT) { int v = lh[tid]; if (v) atomicAdd(&lc[tid], v); }
}

// ------- scan buckets -> boff/gcur, rowoff[N]=E; label starts (pad 64) -------
__global__ __launch_bounds__(256) void scan_master(
    const int* __restrict__ bcnt, const int* __restrict__ lc,
    int* __restrict__ boff, int* __restrict__ gcur, int* __restrict__ rowoff,
    int* __restrict__ lstart, int NB, int N, int E) {
    __shared__ int s[256];
    int tid = threadIdx.x;
    int own = (tid < NB) ? bcnt[tid] : 0;
    s[tid] = own;
    __syncthreads();
    for (int d = 1; d < 256; d <<= 1) {
        int v = (tid >= d) ? s[tid - d] : 0;
        __syncthreads();
        s[tid] += v;
        __syncthreads();
    }
    int excl = s[tid] - own;
    if (tid < NB) { boff[tid] = excl; gcur[tid] = excl; }
    if (tid == 0) {
        boff[NB] = E; rowoff[N] = E;
        int run = 0;
        for (int l = 0; l < NT; ++l) {
            lstart[l] = run;
            run += (lc[l] + 63) & ~63;
        }
    }
}

// ------- node scatter: build iperm (orig -> label-sorted slot) -------
__global__ void scatter_nodes(const int* __restrict__ labels, const int* __restrict__ lstart,
                              int* __restrict__ lcur, int* __restrict__ iperm, int N) {
    int n = blockIdx.x * 256 + threadIdx.x;
    int lab = (n < N) ? labels[n] : -1;
    int lane = threadIdx.x & 63;
    for (int l = 0; l < NT; ++l) {
        unsigned long long m = __ballot(lab == l);
        if (m == 0ull) continue;
        int leader = __builtin_ctzll(m);
        int base = 0;
        if (lane == leader) base = atomicAdd(&lcur[l], (int)__popcll(m));
        base = __shfl(base, leader, 64);
        if (lab == l) {
            int prefix = (int)__popcll(m & ((1ull << lane) - 1ull));
            iperm[n] = lstart[l] + base + prefix;
        }
    }
}

// ------- pass B: scatter edges into dst-bucket regions; src translated to slot -------
// earr record: x = iperm[src] | (dst&255)<<16 ; y = w fp32
__global__ __launch_bounds__(512) void scatter_edges(
    const int* __restrict__ src, const int* __restrict__ dst, const float* __restrict__ w,
    const int* __restrict__ iperm, int* __restrict__ gcur, uint2* __restrict__ earr, int E) {
    __shared__ int h[256];
    __shared__ int basearr[256];
    int tid = threadIdx.x;
    if (tid < 256) h[tid] = 0;
    __syncthreads();
    int base = blockIdx.x * 4096;
    int b[8], rank[8], px[8]; float wv[8];
#pragma unroll
    for (int k = 0; k < 8; ++k) {
        int e = base + k * 512 + tid;
        if (e < E) {
            int d = dst[e];
            b[k] = ((unsigned)d) >> 8;
            px[k] = iperm[src[e]] | ((d & 255) << 16);
            wv[k] = w[e];
            rank[k] = atomicAdd(&h[b[k]], 1);
        } else b[k] = -1;
    }
    __syncthreads();
    if (tid < 256) { int c = h[tid]; basearr[tid] = c ? atomicAdd(&gcur[tid], c) : 0; }
    __syncthreads();
#pragma unroll
    for (int k = 0; k < 8; ++k) {
        if (b[k] >= 0) {
            int pos = basearr[b[k]] + rank[k];
            earr[pos] = make_uint2((unsigned)px[k], __float_as_uint(wv[k]));
        }
    }
}

// ------- pass C: within-bucket counting sort -> rowoff + final 4B edge records -------
// final record: (w_bf16 << 16) | src_slot
__global__ __launch_bounds__(1024) void bucket_sort(
    const uint2* __restrict__ earr, const int* __restrict__ boff,
    int* __restrict__ rowoff, unsigned int* __restrict__ edata, int N) {
    int b = blockIdx.x;
    int s = boff[b], e = boff[b + 1];
    __shared__ int cnt[256], off[256];
    int tid = threadIdx.x;
    if (tid < 256) cnt[tid] = 0;
    __syncthreads();
    for (int i = s + tid; i < e; i += 1024) atomicAdd(&cnt[(earr[i].x >> 16) & 255], 1);
    __syncthreads();
    if (tid < 256) off[tid] = cnt[tid];
    __syncthreads();
    for (int d = 1; d < 256; d <<= 1) {
        int v = 0;
        if (tid < 256 && tid >= d) v = off[tid - d];
        __syncthreads();
        if (tid < 256) off[tid] += v;
        __syncthreads();
    }
    if (tid < 256) {
        int excl = off[tid] - cnt[tid];
        int node = b * 256 + tid;
        if (node < N) rowoff[node] = s + excl;
        off[tid] = excl;
    }
    __syncthreads();
    for (int i = s + tid; i < e; i += 1024) {
        uint2 r = earr[i];
        int d = (r.x >> 16) & 255;
        int k = atomicAdd(&off[d], 1);
        edata[s + k] = (f2bf_bits(__uint_as_float(r.y)) << 16) | (r.x & 0xffff);
    }
}

// ---------------- cast x (fp32) -> bf16, scattered into slot rows ----------------
__global__ void cast_x(const float* __restrict__ x, const int* __restrict__ iperm,
                       unsigned short* __restrict__ xb, int total4) {
    int i = blockIdx.x * 256 + threadIdx.x;
    if (i < total4) {
        float4 v = ((const float4*)x)[i];
        unsigned int lo = f2bf_bits(v.x) | (f2bf_bits(v.y) << 16);
        unsigned int hi = f2bf_bits(v.z) | (f2bf_bits(v.w) << 16);
        int slot = iperm[i >> 6];
        ((uint2*)xb)[(size_t)slot * 64 + (i & 63)] = make_uint2(lo, hi);
    }
}

// ---------------- cast all W -> bf16 B-fragment swizzled (+ k-remap) + permuted biases ----
// Wswz address: lab*FEAT*OUTF + k0*32*OUTF + n*32 + q*8 + j ; element = W[lab][k_src][n]
// layer 1: k_src = k_slot (x is natural); layers 2/3: k_src = nat_of(k_slot) (pi-stored input)
__global__ void cast_w_all(const float* __restrict__ W1, const float* __restrict__ W2,
                           const float* __restrict__ W3, const float* __restrict__ b1,
                           const float* __restrict__ b2,
                           unsigned short* __restrict__ W1b, unsigned short* __restrict__ W2b,
                           unsigned short* __restrict__ W3b, float* __restrict__ biasPerm) {
    const int S = NT * FEAT * FEAT;
    const int S3 = NT * FEAT * OUT3;
    int idx = blockIdx.x * 256 + threadIdx.x;
    if (idx < 2 * S + S3) {
        const float* W; unsigned short* D; int OUTF; int t; bool remap;
        if (idx < S)          { W = W1; D = W1b; OUTF = FEAT; t = idx;         remap = false; }
        else if (idx < 2 * S) { W = W2; D = W2b; OUTF = FEAT; t = idx - S;     remap = true; }
        else                  { W = W3; D = W3b; OUTF = OUT3; t = idx - 2 * S; remap = true; }
        int n = t % OUTF;
        int r = t / OUTF;              // lab*256 + k_slot
        int j = r & 7, q = (r >> 3) & 3, k0 = (r >> 5) & 7, lab = r >> 8;
        int k_slot = k0 * 32 + q * 8 + j;
        int k_src = remap ? nat_of(k_slot) : k_slot;
        float f = W[((size_t)(lab * FEAT + k_src)) * OUTF + n];
        D[(((size_t)lab * 8 + k0) * OUTF + n) * 32 + q * 8 + j] = (unsigned short)f2bf_bits(f);
    } else {
        int p = idx - (2 * S + S3);
        if (p < 256) biasPerm[p] = b1[nat_of(p)];
        else if (p < 512) biasPerm[p] = b2[nat_of(p - 256) ];
    }
}

// ---------------- proj 256-out: dense 64 slots x 256 outs per block ----------------
__global__ __launch_bounds__(256) void proj256_kernel(
    const unsigned short* __restrict__ xb, const unsigned short* __restrict__ Wswz,
    const int* __restrict__ lstart, unsigned short* __restrict__ outp) {
    int warp = threadIdx.x >> 6;
    int lane = threadIdx.x & 63;
    int m0 = blockIdx.x * 64;
    int lab = (m0 >= lstart[1]) + (m0 >= lstart[2]) + (m0 >= lstart[3]);
    int q = lane >> 4, c = lane & 15;
    int n0 = warp * 64;

    const unsigned short* abase = xb + (size_t)m0 * FEAT + (size_t)c * FEAT + q * 8;
    const unsigned short* bb = Wswz + (size_t)lab * FEAT * 256 + (size_t)(n0 + c) * 32 + q * 8;

    f32x4 acc[4][4] = {};
#pragma unroll
    for (int k0 = 0; k0 < 8; ++k0) {
        bf16x8 a[4];
#pragma unroll
        for (int t = 0; t < 4; ++t) a[t] = *(const bf16x8*)(abase + (size_t)t * 16 * FEAT + k0 * 32);
        const unsigned short* bk = bb + (size_t)k0 * 32 * 256;
#pragma unroll
        for (int u = 0; u < 4; ++u) {
            bf16x8 bfrag = *(const bf16x8*)(bk + u * 512);
#pragma unroll
            for (int t = 0; t < 4; ++t)
                acc[t][u] = __builtin_amdgcn_mfma_f32_16x16x32_bf16(a[t], bfrag, acc[t][u], 0, 0, 0);
        }
    }
    // pi-store: row = m0+t*16+q*4+r ; lane writes 4 bf16 (u=0..3) at p = n0 + c*4 + u
    uint2* ov = (uint2*)outp;
#pragma unroll
    for (int t = 0; t < 4; ++t) {
#pragma unroll
        for (int r = 0; r < 4; ++r) {
            int row = m0 + t * 16 + q * 4 + r;
            unsigned int lo = f2bf_bits(acc[t][0][r]) | (f2bf_bits(acc[t][1][r]) << 16);
            unsigned int hi = f2bf_bits(acc[t][2][r]) | (f2bf_bits(acc[t][3][r]) << 16);
            ov[(size_t)row * 64 + (n0 >> 2) + c] = make_uint2(lo, hi);
        }
    }
}

// ---------------- proj 64-out: dense 64 slots x 64 outs per block (warp = m-subtile) ----
__global__ __launch_bounds__(256) void proj64_kernel(
    const unsigned short* __restrict__ xb, const unsigned short* __restrict__ Wswz,
    const int* __restrict__ lstart, unsigned short* __restrict__ outp) {
    int warp = threadIdx.x >> 6;
    int lane = threadIdx.x & 63;
    int m0 = blockIdx.x * 64;
    int lab = (m0 >= lstart[1]) + (m0 >= lstart[2]) + (m0 >= lstart[3]);
    int q = lane >> 4, c = lane & 15;
    int mb = m0 + warp * 16;

    const unsigned short* arow = xb + (size_t)(mb + c) * FEAT + q * 8;
    const unsigned short* bb = Wswz + (size_t)lab * FEAT * OUT3 + (size_t)c * 32 + q * 8;

    f32x4 acc[4] = {};
#pragma unroll
    for (int k0 = 0; k0 < 8; ++k0) {
        bf16x8 a = *(const bf16x8*)(arow + k0 * 32);
        const unsigned short* bk = bb + (size_t)k0 * 32 * OUT3;
#pragma unroll
        for (int u = 0; u < 4; ++u) {
            bf16x8 bfrag = *(const bf16x8*)(bk + u * 512);
            acc[u] = __builtin_amdgcn_mfma_f32_16x16x32_bf16(a, bfrag, acc[u], 0, 0, 0);
        }
    }
    uint2* ov = (uint2*)outp;
#pragma unroll
    for (int r = 0; r < 4; ++r) {
        int row = mb + q * 4 + r;
        unsigned int lo = f2bf_bits(acc[0][r]) | (f2bf_bits(acc[1][r]) << 16);
        unsigned int hi = f2bf_bits(acc[2][r]) | (f2bf_bits(acc[3][r]) << 16);
        ov[(size_t)row * 16 + c] = make_uint2(lo, hi);
    }
}

// ---------------- aggregation, 256-feat: one wave per node ----------------
// edge record: (w_bf16<<16) | src_slot.  lane holds stored pos p=4*lane..4*lane+3 as uint2.
__global__ __launch_bounds__(256) void agg256_kernel(
    const uint2* __restrict__ sup, const int* __restrict__ rowoff,
    const unsigned int* __restrict__ edata, const int* __restrict__ iperm,
    const float* __restrict__ biasPerm, uint2* __restrict__ outp, int N) {
    int warp = __builtin_amdgcn_readfirstlane((int)(threadIdx.x >> 6));
    int node = (int)blockIdx.x * 4 + warp;
    if (node >= N) return;
    int lane = threadIdx.x & 63;
    int s = __builtin_amdgcn_readfirstlane(rowoff[node]);
    int e = __builtin_amdgcn_readfirstlane(rowoff[node + 1]);
    int slot = __builtin_amdgcn_readfirstlane(iperm[node]);
    float a0 = 0.f, a1 = 0.f, a2 = 0.f, a3 = 0.f;
    int j = s;
    for (; j + 8 <= e; j += 8) {
        unsigned int ed[8]; uint2 v[8];
#pragma unroll
        for (int u = 0; u < 8; ++u) ed[u] = edata[j + u];
#pragma unroll
        for (int u = 0; u < 8; ++u) v[u] = sup[(size_t)(ed[u] & 0xffff) * 64 + lane];
#pragma unroll
        for (int u = 0; u < 8; ++u) {
            float w = __uint_as_float(ed[u] & 0xffff0000u);
            a0 += w * bfl(v[u].x); a1 += w * bfh(v[u].x);
            a2 += w * bfl(v[u].y); a3 += w * bfh(v[u].y);
        }
    }
    if (j < e) {   // masked tail (<=7 real edges)
        unsigned int ed[8]; float wm[8]; uint2 v[8];
#pragma unroll
        for (int u = 0; u < 8; ++u) {
            int jj = j + u;
            int jc = (jj < e) ? jj : e - 1;
            ed[u] = edata[jc];
            wm[u] = (jj < e) ? __uint_as_float(ed[u] & 0xffff0000u) : 0.f;
        }
#pragma unroll
        for (int u = 0; u < 8; ++u) v[u] = sup[(size_t)(ed[u] & 0xffff) * 64 + lane];
#pragma unroll
        for (int u = 0; u < 8; ++u) {
            a0 += wm[u] * bfl(v[u].x); a1 += wm[u] * bfh(v[u].x);
            a2 += wm[u] * bfl(v[u].y); a3 += wm[u] * bfh(v[u].y);
        }
    }
    float4 b = ((const float4*)biasPerm)[lane];
    a0 = fmaxf(a0 + b.x, 0.f);
    a1 = fmaxf(a1 + b.y, 0.f);
    a2 = fmaxf(a2 + b.z, 0.f);
    a3 = fmaxf(a3 + b.w, 0.f);
    unsigned int lo = f2bf_bits(a0) | (f2bf_bits(a1) << 16);
    unsigned int hi = f2bf_bits(a2) | (f2bf_bits(a3) << 16);
    outp[(size_t)slot * 64 + lane] = make_uint2(lo, hi);
}

// ---------------- aggregation, 64-feat: one wave per node (lane = stored pos), fp32 out --
__global__ __launch_bounds__(256) void agg64_kernel(
    const unsigned short* __restrict__ sup, const int* __restrict__ rowoff,
    const unsigned int* __restrict__ edata, const float* __restrict__ b3,
    float* __restrict__ outp, int N) {
    int warp = __builtin_amdgcn_readfirstlane((int)(threadIdx.x >> 6));
    int node = (int)blockIdx.x * 4 + warp;
    if (node >= N) return;
    int lane = threadIdx.x & 63;
    int s = __builtin_amdgcn_readfirstlane(rowoff[node]);
    int e = __builtin_amdgcn_readfirstlane(rowoff[node + 1]);
    float a = 0.f;
    int j = s;
    for (; j + 8 <= e; j += 8) {
        unsigned int ed[8]; unsigned short v[8];
#pragma unroll
        for (int u = 0; u < 8; ++u) ed[u] = edata[j + u];
#pragma unroll
        for (int u = 0; u < 8; ++u) v[u] = sup[(size_t)(ed[u] & 0xffff) * 64 + lane];
#pragma unroll
        for (int u = 0; u < 8; ++u)
            a += __uint_as_float(ed[u] & 0xffff0000u) * __uint_as_float((unsigned int)v[u] << 16);
    }
    if (j < e) {
        unsigned int ed[8]; float wm[8]; unsigned short v[8];
#pragma unroll
        for (int u = 0; u < 8; ++u) {
            int jj = j + u;
            int jc = (jj < e) ? jj : e - 1;
            ed[u] = edata[jc];
            wm[u] = (jj < e) ? __uint_as_float(ed[u] & 0xffff0000u) : 0.f;
        }
#pragma unroll
        for (int u = 0; u < 8; ++u) v[u] = sup[(size_t)(ed[u] & 0xffff) * 64 + lane];
#pragma unroll
        for (int u = 0; u < 8; ++u)
            a += wm[u] * __uint_as_float((unsigned int)v[u] << 16);
    }
    int natp = (((lane & 3) << 4) | (lane >> 2));    // un-permute pi within the 64 outs
    outp[(size_t)node * 64 + natp] = a + b3[natp];
}

extern "C" void kernel_launch(void* const* d_in, const int* in_sizes, int n_in,
                              void* d_out, int out_size, void* d_ws, size_t ws_size,
                              hipStream_t stream) {
    const float* x        = (const float*)d_in[0];
    const int*   edge_src = (const int*)d_in[1];
    const int*   edge_dst = (const int*)d_in[2];
    const float* edge_w   = (const float*)d_in[3];
    const int*   labels   = (const int*)d_in[4];
    const float* W1 = (const float*)d_in[5];
    const float* b1 = (const float*)d_in[6];
    const float* W2 = (const float*)d_in[7];
    const float* b2 = (const float*)d_in[8];
    const float* W3 = (const float*)d_in[9];
    const float* b3 = (const float*)d_in[10];

    const int N = in_sizes[0] / FEAT;
    const int E = in_sizes[1];
    const int NB = (N + 255) >> 8;                    // dst buckets (orig id space)
    const int G64 = (N + NT * 64 + 63) / 64;          // slot-space 64-row tiles (upper bound)
    const int slotCap = G64 * 64;

    // ---- workspace carve (256B aligned) ----
    char* p = (char*)d_ws;
    auto alloc = [&](size_t bytes) -> char* {
        char* r = p;
        p += (bytes + 255) & ~(size_t)255;
        return r;
    };
    unsigned short* bufA = (unsigned short*)alloc((size_t)slotCap * FEAT * 2);
    unsigned short* bufB = (unsigned short*)alloc((size_t)slotCap * FEAT * 2);
    unsigned short* W1b  = (unsigned short*)alloc((size_t)NT * FEAT * FEAT * 2);
    unsigned short* W2b  = (unsigned short*)alloc((size_t)NT * FEAT * FEAT * 2);
    unsigned short* W3b  = (unsigned short*)alloc((size_t)NT * FEAT * OUT3 * 2);
    float*        biasPerm = (float*)alloc(512 * 4);
    int*          rowoff = (int*)alloc((size_t)(N + 1) * 4);
    unsigned int* edata  = (unsigned int*)alloc((size_t)E * 4);
    int*          iperm  = (int*)alloc((size_t)N * 4);
    int*          bcnt   = (int*)alloc(256 * 4);
    int*          boff   = (int*)alloc(257 * 4);
    int*          gcur   = (int*)alloc(256 * 4);
    int*          lc     = (int*)alloc(64);
    int*          lcur   = (int*)alloc(64);
    int*          lstart = (int*)alloc(64);
    // bucket-sort staging ALIASED onto bufA (consumed by bucket_sort before cast_x writes)
    uint2* earr = (uint2*)bufA;   // E*8 = 12.8MB <= slotCap*512B

    const int nbEB = (E + 4095) / 4096;

    // ---- CSR build + label-sort ----
    zero_small<<<1, 256, 0, stream>>>(bcnt, lc, lcur);
    pass_a<<<nbEB, 512, 0, stream>>>(edge_dst, labels, bcnt, lc, E, N);
    scan_master<<<1, 256, 0, stream>>>(bcnt, lc, boff, gcur, rowoff, lstart, NB, N, E);
    scatter_nodes<<<(N + 255) / 256, 256, 0, stream>>>(labels, lstart, lcur, iperm, N);
    scatter_edges<<<nbEB, 512, 0, stream>>>(edge_src, edge_dst, edge_w, iperm, gcur, earr, E);
    bucket_sort<<<NB, 1024, 0, stream>>>(earr, boff, rowoff, edata, N);

    // ---- casts (cast_x overwrites bufA AFTER bucket_sort consumed earr) ----
    cast_x<<<((N * 64) + 255) / 256, 256, 0, stream>>>(x, iperm, bufA, N * 64);
    {
        int total = 2 * NT * FEAT * FEAT + NT * FEAT * OUT3 + 512;
        cast_w_all<<<(total + 255) / 256, 256, 0, stream>>>(W1, W2, W3, b1, b2, W1b, W2b, W3b, biasPerm);
    }

    // ---- layer 1 ----
    proj256_kernel<<<G64, 256, 0, stream>>>(bufA, W1b, lstart, bufB);
    agg256_kernel<<<(N + 3) / 4, 256, 0, stream>>>((const uint2*)bufB, rowoff, edata, iperm, biasPerm, (uint2*)bufA, N);
    // ---- layer 2 ----
    proj256_kernel<<<G64, 256, 0, stream>>>(bufA, W2b, lstart, bufB);
    agg256_kernel<<<(N + 3) / 4, 256, 0, stream>>>((const uint2*)bufB, rowoff, edata, iperm, biasPerm + 256, (uint2*)bufA, N);
    // ---- layer 3 ----
    proj64_kernel<<<G64, 256, 0, stream>>>(bufA, W3b, lstart, bufB);
    agg64_kernel<<<(N + 3) / 4, 256, 0, stream>>>(bufB, rowoff, edata, b3, (float*)d_out, N);
}

// Round 6
// 501.800 us; speedup vs baseline: 2.3933x; 1.0088x over previous
//
#include <hip/hip_runtime.h>
#include <hip/hip_bf16.h>

#define NT 4           // node types (labels)
#define FEAT 256       // nfeat == nhid
#define OUT3 64        // nclass

typedef __bf16 bf16x8 __attribute__((ext_vector_type(8)));
typedef float  f32x4  __attribute__((ext_vector_type(4)));

__device__ inline unsigned int f2bf_bits(float f) {
    __hip_bfloat16 h = __float2bfloat16(f);   // RNE
    unsigned short u;
    __builtin_memcpy(&u, &h, 2);
    return (unsigned int)u;
}
__device__ inline float bfl(unsigned int u) { return __uint_as_float(u << 16); }
__device__ inline float bfh(unsigned int u) { return __uint_as_float(u & 0xffff0000u); }
// stored feature pos p (pi order) -> natural feature index, within each 64-block
__device__ __host__ inline int nat_of(int p) {
    int lo = p & 63;
    return (p & ~63) | (((lo & 3) << 4) | (lo >> 2));
}

// ---------------- pass A: dst-bucket histogram (dst>>8) + label histogram ----------------
__global__ __launch_bounds__(512) void pass_a(const int* __restrict__ dst,
                                              const int* __restrict__ labels,
                                              int* __restrict__ bcnt, int* __restrict__ lc,
                                              int E, int N) {
    __shared__ int h[256];
    __shared__ int lh[NT];
    int tid = threadIdx.x;
    if (tid < 256) h[tid] = 0;
    if (tid < NT) lh[tid] = 0;
    __syncthreads();
    int base = blockIdx.x * 4096;
#pragma unroll
    for (int k = 0; k < 8; ++k) {
        int e = base + k * 512 + tid;
        if (e < E) atomicAdd(&h[((unsigned)dst[e]) >> 8], 1);
    }
#pragma unroll
    for (int k = 0; k < 8; ++k) {
        int i = base + k * 512 + tid;
        if (i < N) atomicAdd(&lh[labels[i]], 1);
    }
    __syncthreads();
    if (tid < 256) { int v = h[tid]; if (v) atomicAdd(&bcnt[tid], v); }
    if (tid < NT) { int v = lh[tid]; if (v) atomicAdd(&lc[tid], v); }
}

// ------- scan buckets -> boff/gcur, rowoff[N]=E; label starts (pad 64) -------
__global__ __launch_bounds__(256) void scan_master(
    const int* __restrict__ bcnt, const int* __restrict__ lc,
    int* __restrict__ boff, int* __restrict__ gcur, int* __restrict__ rowoff,
    int* __restrict__ lstart, int NB, int N, int E) {
    __shared__ int s[256];
    int tid = threadIdx.x;
    int own = (tid < NB) ? bcnt[tid] : 0;
    s[tid] = own;
    __syncthreads();
    for (int d = 1; d < 256; d <<= 1) {
        int v = (tid >= d) ? s[tid - d] : 0;
        __syncthreads();
        s[tid] += v;
        __syncthreads();
    }
    int excl = s[tid] - own;
    if (tid < NB) { boff[tid] = excl; gcur[tid] = excl; }
    if (tid == 0) {
        boff[NB] = E; rowoff[N] = E;
        int run = 0;
        for (int l = 0; l < NT; ++l) {
            lstart[l] = run;
            run += (lc[l] + 63) & ~63;
        }
    }
}

// ------- node scatter: build iperm (orig -> label-sorted slot) -------
__global__ void scatter_nodes(const int* __restrict__ labels, const int* __restrict__ lstart,
                              int* __restrict__ lcur, int* __restrict__ iperm, int N) {
    int n = blockIdx.x * 256 + threadIdx.x;
    int lab = (n < N) ? labels[n] : -1;
    int lane = threadIdx.x & 63;
    for (int l = 0; l < NT; ++l) {
        unsigned long long m = __ballot(lab == l);
        if (m == 0ull) continue;
        int leader = __builtin_ctzll(m);
        int base = 0;
        if (lane == leader) base = atomicAdd(&lcur[l], (int)__popcll(m));
        base = __shfl(base, leader, 64);
        if (lab == l) {
            int prefix = (int)__popcll(m & ((1ull << lane) - 1ull));
            iperm[n] = lstart[l] + base + prefix;
        }
    }
}

// ------- pass B: scatter edges into dst-bucket regions; src translated to slot -------
// earr record: x = iperm[src] | (dst&255)<<16 ; y = w fp32
__global__ __launch_bounds__(512) void scatter_edges(
    const int* __restrict__ src, const int* __restrict__ dst, const float* __restrict__ w,
    const int* __restrict__ iperm, int* __restrict__ gcur, uint2* __restrict__ earr, int E) {
    __shared__ int h[256];
    __shared__ int basearr[256];
    int tid = threadIdx.x;
    if (tid < 256) h[tid] = 0;
    __syncthreads();
    int base = blockIdx.x * 4096;
    int b[8], rank[8], px[8]; float wv[8];
#pragma unroll
    for (int k = 0; k < 8; ++k) {
        int e = base + k * 512 + tid;
        if (e < E) {
            int d = dst[e];
            b[k] = ((unsigned)d) >> 8;
            px[k] = iperm[src[e]] | ((d & 255) << 16);
            wv[k] = w[e];
            rank[k] = atomicAdd(&h[b[k]], 1);
        } else b[k] = -1;
    }
    __syncthreads();
    if (tid < 256) { int c = h[tid]; basearr[tid] = c ? atomicAdd(&gcur[tid], c) : 0; }
    __syncthreads();
#pragma unroll
    for (int k = 0; k < 8; ++k) {
        if (b[k] >= 0) {
            int pos = basearr[b[k]] + rank[k];
            earr[pos] = make_uint2((unsigned)px[k], __float_as_uint(wv[k]));
        }
    }
}

// ------- pass C: within-bucket counting sort -> rowoff + final 4B edge records -------
// final record: (w_bf16 << 16) | src_slot
__global__ __launch_bounds__(1024) void bucket_sort(
    const uint2* __restrict__ earr, const int* __restrict__ boff,
    int* __restrict__ rowoff, unsigned int* __restrict__ edata, int N) {
    int b = blockIdx.x;
    int s = boff[b], e = boff[b + 1];
    __shared__ int cnt[256], off[256];
    int tid = threadIdx.x;
    if (tid < 256) cnt[tid] = 0;
    __syncthreads();
    for (int i = s + tid; i < e; i += 1024) atomicAdd(&cnt[(earr[i].x >> 16) & 255], 1);
    __syncthreads();
    if (tid < 256) off[tid] = cnt[tid];
    __syncthreads();
    for (int d = 1; d < 256; d <<= 1) {
        int v = 0;
        if (tid < 256 && tid >= d) v = off[tid - d];
        __syncthreads();
        if (tid < 256) off[tid] += v;
        __syncthreads();
    }
    if (tid < 256) {
        int excl = off[tid] - cnt[tid];
        int node = b * 256 + tid;
        if (node < N) rowoff[node] = s + excl;
        off[tid] = excl;
    }
    __syncthreads();
    for (int i = s + tid; i < e; i += 1024) {
        uint2 r = earr[i];
        int d = (r.x >> 16) & 255;
        int k = atomicAdd(&off[d], 1);
        edata[s + k] = (f2bf_bits(__uint_as_float(r.y)) << 16) | (r.x & 0xffff);
    }
}

// ---------------- cast x (fp32) -> bf16, scattered into slot rows, half-split ----------
// natural feat f = 4*(i&63); half = f>=128; within-half uint2 idx = i&31
__global__ void cast_x(const float* __restrict__ x, const int* __restrict__ iperm,
                       unsigned short* __restrict__ actLo, unsigned short* __restrict__ actHi,
                       int total4) {
    int i = blockIdx.x * 256 + threadIdx.x;
    if (i < total4) {
        float4 v = ((const float4*)x)[i];
        unsigned int lo = f2bf_bits(v.x) | (f2bf_bits(v.y) << 16);
        unsigned int hi = f2bf_bits(v.z) | (f2bf_bits(v.w) << 16);
        int slot = iperm[i >> 6];
        unsigned short* dst = ((i & 63) >= 32) ? actHi : actLo;
        ((uint2*)dst)[(size_t)slot * 32 + (i & 31)] = make_uint2(lo, hi);
    }
}

// ---------------- cast all W -> bf16 B-fragment swizzled (+ k-remap) + permuted biases ----
__global__ void cast_w_all(const float* __restrict__ W1, const float* __restrict__ W2,
                           const float* __restrict__ W3, const float* __restrict__ b1,
                           const float* __restrict__ b2,
                           unsigned short* __restrict__ W1b, unsigned short* __restrict__ W2b,
                           unsigned short* __restrict__ W3b, float* __restrict__ biasPerm) {
    const int S = NT * FEAT * FEAT;
    const int S3 = NT * FEAT * OUT3;
    int idx = blockIdx.x * 256 + threadIdx.x;
    if (idx < 2 * S + S3) {
        const float* W; unsigned short* D; int OUTF; int t; bool remap;
        if (idx < S)          { W = W1; D = W1b; OUTF = FEAT; t = idx;         remap = false; }
        else if (idx < 2 * S) { W = W2; D = W2b; OUTF = FEAT; t = idx - S;     remap = true; }
        else                  { W = W3; D = W3b; OUTF = OUT3; t = idx - 2 * S; remap = true; }
        int n = t % OUTF;
        int r = t / OUTF;              // lab*256 + k_slot
        int j = r & 7, q = (r >> 3) & 3, k0 = (r >> 5) & 7, lab = r >> 8;
        int k_slot = k0 * 32 + q * 8 + j;
        int k_src = remap ? nat_of(k_slot) : k_slot;
        float f = W[((size_t)(lab * FEAT + k_src)) * OUTF + n];
        D[(((size_t)lab * 8 + k0) * OUTF + n) * 32 + q * 8 + j] = (unsigned short)f2bf_bits(f);
    } else {
        int p = idx - (2 * S + S3);
        if (p < 256) biasPerm[p] = b1[nat_of(p)];
        else if (p < 512) biasPerm[p] = b2[nat_of(p - 256)];
    }
}

// ---------------- proj 256-out: dense 64 slots x 256 outs per block, half-split I/O ------
__global__ __launch_bounds__(256) void proj256_kernel(
    const unsigned short* __restrict__ actLo, const unsigned short* __restrict__ actHi,
    const unsigned short* __restrict__ Wswz, const int* __restrict__ lstart,
    unsigned short* __restrict__ supLo, unsigned short* __restrict__ supHi) {
    int warp = threadIdx.x >> 6;
    int lane = threadIdx.x & 63;
    int m0 = blockIdx.x * 64;
    int lab = (m0 >= lstart[1]) + (m0 >= lstart[2]) + (m0 >= lstart[3]);
    int q = lane >> 4, c = lane & 15;
    int n0 = warp * 64;

    const unsigned short* aLo = actLo + (size_t)(m0 + c) * 128 + q * 8;
    const unsigned short* aHi = actHi + (size_t)(m0 + c) * 128 + q * 8;
    const unsigned short* bb = Wswz + (size_t)lab * FEAT * 256 + (size_t)(n0 + c) * 32 + q * 8;

    f32x4 acc[4][4] = {};
#pragma unroll
    for (int k0 = 0; k0 < 8; ++k0) {
        const unsigned short* abase = (k0 < 4) ? aLo : aHi;
        int koff = (k0 & 3) * 32;
        bf16x8 a[4];
#pragma unroll
        for (int t = 0; t < 4; ++t) a[t] = *(const bf16x8*)(abase + (size_t)t * 2048 + koff);
        const unsigned short* bk = bb + (size_t)k0 * 32 * 256;
#pragma unroll
        for (int u = 0; u < 4; ++u) {
            bf16x8 bfrag = *(const bf16x8*)(bk + u * 512);
#pragma unroll
            for (int t = 0; t < 4; ++t)
                acc[t][u] = __builtin_amdgcn_mfma_f32_16x16x32_bf16(a[t], bfrag, acc[t][u], 0, 0, 0);
        }
    }
    // pi-store: row = m0+t*16+q*4+r ; lane writes p = n0 + c*4 + u -> half n0>>7
    uint2* ov = (uint2*)((n0 >= 128) ? supHi : supLo);
    int cix = ((n0 & 64) >> 2) + c;
#pragma unroll
    for (int t = 0; t < 4; ++t) {
#pragma unroll
        for (int r = 0; r < 4; ++r) {
            int row = m0 + t * 16 + q * 4 + r;
            unsigned int lo = f2bf_bits(acc[t][0][r]) | (f2bf_bits(acc[t][1][r]) << 16);
            unsigned int hi = f2bf_bits(acc[t][2][r]) | (f2bf_bits(acc[t][3][r]) << 16);
            ov[(size_t)row * 32 + cix] = make_uint2(lo, hi);
        }
    }
}

// ---------------- proj 64-out: dense 64 slots x 64 outs per block, half-split input ------
__global__ __launch_bounds__(256) void proj64_kernel(
    const unsigned short* __restrict__ actLo, const unsigned short* __restrict__ actHi,
    const unsigned short* __restrict__ Wswz, const int* __restrict__ lstart,
    unsigned short* __restrict__ outp) {
    int warp = threadIdx.x >> 6;
    int lane = threadIdx.x & 63;
    int m0 = blockIdx.x * 64;
    int lab = (m0 >= lstart[1]) + (m0 >= lstart[2]) + (m0 >= lstart[3]);
    int q = lane >> 4, c = lane & 15;
    int mb = m0 + warp * 16;

    const unsigned short* aLo = actLo + (size_t)(mb + c) * 128 + q * 8;
    const unsigned short* aHi = actHi + (size_t)(mb + c) * 128 + q * 8;
    const unsigned short* bb = Wswz + (size_t)lab * FEAT * OUT3 + (size_t)c * 32 + q * 8;

    f32x4 acc[4] = {};
#pragma unroll
    for (int k0 = 0; k0 < 8; ++k0) {
        const unsigned short* abase = (k0 < 4) ? aLo : aHi;
        bf16x8 a = *(const bf16x8*)(abase + (k0 & 3) * 32);
        const unsigned short* bk = bb + (size_t)k0 * 32 * OUT3;
#pragma unroll
        for (int u = 0; u < 4; ++u) {
            bf16x8 bfrag = *(const bf16x8*)(bk + u * 512);
            acc[u] = __builtin_amdgcn_mfma_f32_16x16x32_bf16(a, bfrag, acc[u], 0, 0, 0);
        }
    }
    uint2* ov = (uint2*)outp;
#pragma unroll
    for (int r = 0; r < 4; ++r) {
        int row = mb + q * 4 + r;
        unsigned int lo = f2bf_bits(acc[0][r]) | (f2bf_bits(acc[1][r]) << 16);
        unsigned int hi = f2bf_bits(acc[2][r]) | (f2bf_bits(acc[3][r]) << 16);
        ov[(size_t)row * 16 + c] = make_uint2(lo, hi);
    }
}

// ------- aggregation over ONE feature half (128 feats): one wave per node, unroll 16 -----
// sup half row = 64 uints (256B). lane handles stored pos p = half*128 + 2*lane, +1.
__global__ __launch_bounds__(256) void agg256h_kernel(
    const unsigned int* __restrict__ sup, const int* __restrict__ rowoff,
    const unsigned int* __restrict__ edata, const int* __restrict__ iperm,
    const float* __restrict__ biasHalf, unsigned int* __restrict__ outp, int N) {
    int warp = __builtin_amdgcn_readfirstlane((int)(threadIdx.x >> 6));
    int node = (int)blockIdx.x * 4 + warp;
    if (node >= N) return;
    int lane = threadIdx.x & 63;
    int s = __builtin_amdgcn_readfirstlane(rowoff[node]);
    int e = __builtin_amdgcn_readfirstlane(rowoff[node + 1]);
    int slot = __builtin_amdgcn_readfirstlane(iperm[node]);
    float a0 = 0.f, a1 = 0.f;
    int j = s;
    for (; j + 16 <= e; j += 16) {
        unsigned int ed[16], v[16];
#pragma unroll
        for (int u = 0; u < 16; ++u) ed[u] = edata[j + u];
#pragma unroll
        for (int u = 0; u < 16; ++u) v[u] = sup[(size_t)(ed[u] & 0xffff) * 64 + lane];
#pragma unroll
        for (int u = 0; u < 16; ++u) {
            float w = __uint_as_float(ed[u] & 0xffff0000u);
            a0 += w * bfl(v[u]); a1 += w * bfh(v[u]);
        }
    }
    if (j < e) {   // masked tail (<=15 real edges)
        unsigned int ed[16], v[16]; float wm[16];
#pragma unroll
        for (int u = 0; u < 16; ++u) {
            int jj = j + u;
            int jc = (jj < e) ? jj : e - 1;
            ed[u] = edata[jc];
            wm[u] = (jj < e) ? __uint_as_float(ed[u] & 0xffff0000u) : 0.f;
        }
#pragma unroll
        for (int u = 0; u < 16; ++u) v[u] = sup[(size_t)(ed[u] & 0xffff) * 64 + lane];
#pragma unroll
        for (int u = 0; u < 16; ++u) { a0 += wm[u] * bfl(v[u]); a1 += wm[u] * bfh(v[u]); }
    }
    float2 b = ((const float2*)biasHalf)[lane];
    a0 = fmaxf(a0 + b.x, 0.f);
    a1 = fmaxf(a1 + b.y, 0.f);
    outp[(size_t)slot * 64 + lane] = f2bf_bits(a0) | (f2bf_bits(a1) << 16);
}

// ---------------- aggregation, 64-feat: one wave per node (lane = stored pos), fp32 out --
__global__ __launch_bounds__(256) void agg64_kernel(
    const unsigned short* __restrict__ sup, const int* __restrict__ rowoff,
    const unsigned int* __restrict__ edata, const float* __restrict__ b3,
    float* __restrict__ outp, int N) {
    int warp = __builtin_amdgcn_readfirstlane((int)(threadIdx.x >> 6));
    int node = (int)blockIdx.x * 4 + warp;
    if (node >= N) return;
    int lane = threadIdx.x & 63;
    int s = __builtin_amdgcn_readfirstlane(rowoff[node]);
    int e = __builtin_amdgcn_readfirstlane(rowoff[node + 1]);
    float a = 0.f;
    int j = s;
    for (; j + 8 <= e; j += 8) {
        unsigned int ed[8]; unsigned short v[8];
#pragma unroll
        for (int u = 0; u < 8; ++u) ed[u] = edata[j + u];
#pragma unroll
        for (int u = 0; u < 8; ++u) v[u] = sup[(size_t)(ed[u] & 0xffff) * 64 + lane];
#pragma unroll
        for (int u = 0; u < 8; ++u)
            a += __uint_as_float(ed[u] & 0xffff0000u) * __uint_as_float((unsigned int)v[u] << 16);
    }
    if (j < e) {
        unsigned int ed[8]; float wm[8]; unsigned short v[8];
#pragma unroll
        for (int u = 0; u < 8; ++u) {
            int jj = j + u;
            int jc = (jj < e) ? jj : e - 1;
            ed[u] = edata[jc];
            wm[u] = (jj < e) ? __uint_as_float(ed[u] & 0xffff0000u) : 0.f;
        }
#pragma unroll
        for (int u = 0; u < 8; ++u) v[u] = sup[(size_t)(ed[u] & 0xffff) * 64 + lane];
#pragma unroll
        for (int u = 0; u < 8; ++u)
            a += wm[u] * __uint_as_float((unsigned int)v[u] << 16);
    }
    int natp = (((lane & 3) << 4) | (lane >> 2));    // un-permute pi within the 64 outs
    outp[(size_t)node * 64 + natp] = a + b3[natp];
}

extern "C" void kernel_launch(void* const* d_in, const int* in_sizes, int n_in,
                              void* d_out, int out_size, void* d_ws, size_t ws_size,
                              hipStream_t stream) {
    const float* x        = (const float*)d_in[0];
    const int*   edge_src = (const int*)d_in[1];
    const int*   edge_dst = (const int*)d_in[2];
    const float* edge_w   = (const float*)d_in[3];
    const int*   labels   = (const int*)d_in[4];
    const float* W1 = (const float*)d_in[5];
    const float* b1 = (const float*)d_in[6];
    const float* W2 = (const float*)d_in[7];
    const float* b2 = (const float*)d_in[8];
    const float* W3 = (const float*)d_in[9];
    const float* b3 = (const float*)d_in[10];

    const int N = in_sizes[0] / FEAT;
    const int E = in_sizes[1];
    const int NB = (N + 255) >> 8;                    // dst buckets (orig id space)
    const int G64 = (N + NT * 64 + 63) / 64;          // slot-space 64-row tiles (upper bound)
    const int slotCap = G64 * 64;

    // ---- workspace carve (256B aligned) ----
    char* p = (char*)d_ws;
    auto alloc = [&](size_t bytes) -> char* {
        char* r = p;
        p += (bytes + 255) & ~(size_t)255;
        return r;
    };
    unsigned short* bufA = (unsigned short*)alloc((size_t)slotCap * FEAT * 2);
    unsigned short* bufB = (unsigned short*)alloc((size_t)slotCap * FEAT * 2);
    unsigned short* W1b  = (unsigned short*)alloc((size_t)NT * FEAT * FEAT * 2);
    unsigned short* W2b  = (unsigned short*)alloc((size_t)NT * FEAT * FEAT * 2);
    unsigned short* W3b  = (unsigned short*)alloc((size_t)NT * FEAT * OUT3 * 2);
    float*        biasPerm = (float*)alloc(512 * 4);
    int*          rowoff = (int*)alloc((size_t)(N + 1) * 4);
    unsigned int* edata  = (unsigned int*)alloc((size_t)E * 4);
    int*          iperm  = (int*)alloc((size_t)N * 4);
    int*          counters = (int*)alloc(264 * 4);    // bcnt[256] + lc[4] + lcur[4]
    int*          boff   = (int*)alloc(257 * 4);
    int*          gcur   = (int*)alloc(256 * 4);
    int*          lstart = (int*)alloc(64);
    int* bcnt = counters;
    int* lc   = counters + 256;
    int* lcur = counters + 260;

    // half-table views (lo = feats p<128, hi = p>=128), each slotCap*128 ushorts
    unsigned short* actLo = bufA;
    unsigned short* actHi = bufA + (size_t)slotCap * 128;
    unsigned short* supLo = bufB;
    unsigned short* supHi = bufB + (size_t)slotCap * 128;
    // bucket-sort staging ALIASED onto bufA (consumed by bucket_sort before cast_x writes)
    uint2* earr = (uint2*)bufA;   // E*8 = 12.8MB <= bufA 25.6MB

    const int nbEB = (E + 4095) / 4096;

    // ---- CSR build + label-sort ----
    hipMemsetAsync(counters, 0, 264 * 4, stream);
    pass_a<<<nbEB, 512, 0, stream>>>(edge_dst, labels, bcnt, lc, E, N);
    scan_master<<<1, 256, 0, stream>>>(bcnt, lc, boff, gcur, rowoff, lstart, NB, N, E);
    scatter_nodes<<<(N + 255) / 256, 256, 0, stream>>>(labels, lstart, lcur, iperm, N);
    scatter_edges<<<nbEB, 512, 0, stream>>>(edge_src, edge_dst, edge_w, iperm, gcur, earr, E);
    bucket_sort<<<NB, 1024, 0, stream>>>(earr, boff, rowoff, edata, N);

    // ---- casts (cast_x overwrites bufA AFTER bucket_sort consumed earr) ----
    cast_x<<<((N * 64) + 255) / 256, 256, 0, stream>>>(x, iperm, actLo, actHi, N * 64);
    {
        int total = 2 * NT * FEAT * FEAT + NT * FEAT * OUT3 + 512;
        cast_w_all<<<(total + 255) / 256, 256, 0, stream>>>(W1, W2, W3, b1, b2, W1b, W2b, W3b, biasPerm);
    }

    const int aggGrid = (N + 3) / 4;
    // ---- layer 1 ----
    proj256_kernel<<<G64, 256, 0, stream>>>(actLo, actHi, W1b, lstart, supLo, supHi);
    agg256h_kernel<<<aggGrid, 256, 0, stream>>>((const unsigned int*)supLo, rowoff, edata, iperm,
                                                biasPerm + 0, (unsigned int*)actLo, N);
    agg256h_kernel<<<aggGrid, 256, 0, stream>>>((const unsigned int*)supHi, rowoff, edata, iperm,
                                                biasPerm + 128, (unsigned int*)actHi, N);
    // ---- layer 2 ----
    proj256_kernel<<<G64, 256, 0, stream>>>(actLo, actHi, W2b, lstart, supLo, supHi);
    agg256h_kernel<<<aggGrid, 256, 0, stream>>>((const unsigned int*)supLo, rowoff, edata, iperm,
                                                biasPerm + 256, (unsigned int*)actLo, N);
    agg256h_kernel<<<aggGrid, 256, 0, stream>>>((const unsigned int*)supHi, rowoff, edata, iperm,
                                                biasPerm + 384, (unsigned int*)actHi, N);
    // ---- layer 3 ----
    proj64_kernel<<<G64, 256, 0, stream>>>(actLo, actHi, W3b, lstart, bufB);
    agg64_kernel<<<aggGrid, 256, 0, stream>>>(bufB, rowoff, edata, b3, (float*)d_out, N);
}

// Round 7
// 482.305 us; speedup vs baseline: 2.4901x; 1.0404x over previous
//
#include <hip/hip_runtime.h>
#include <hip/hip_bf16.h>

#define NT 4           // node types (labels)
#define FEAT 256       // nfeat == nhid
#define OUT3 64        // nclass

typedef __bf16 bf16x8 __attribute__((ext_vector_type(8)));
typedef float  f32x4  __attribute__((ext_vector_type(4)));

__device__ inline unsigned int f2bf_bits(float f) {
    __hip_bfloat16 h = __float2bfloat16(f);   // RNE
    unsigned short u;
    __builtin_memcpy(&u, &h, 2);
    return (unsigned int)u;
}
__device__ inline float bfl(unsigned int u) { return __uint_as_float(u << 16); }
__device__ inline float bfh(unsigned int u) { return __uint_as_float(u & 0xffff0000u); }
// stored feature pos p (pi order) -> natural feature index, within each 64-block
__device__ __host__ inline int nat_of(int p) {
    int lo = p & 63;
    return (p & ~63) | (((lo & 3) << 4) | (lo >> 2));
}

// ---------------- pass A: dst-bucket histogram (dst>>8) + label histogram ----------------
__global__ __launch_bounds__(512) void pass_a(const int* __restrict__ dst,
                                              const int* __restrict__ labels,
                                              int* __restrict__ bcnt, int* __restrict__ lc,
                                              int E, int N) {
    __shared__ int h[256];
    __shared__ int lh[NT];
    int tid = threadIdx.x;
    if (tid < 256) h[tid] = 0;
    if (tid < NT) lh[tid] = 0;
    __syncthreads();
    int base = blockIdx.x * 4096;
#pragma unroll
    for (int k = 0; k < 8; ++k) {
        int e = base + k * 512 + tid;
        if (e < E) atomicAdd(&h[((unsigned)dst[e]) >> 8], 1);
    }
#pragma unroll
    for (int k = 0; k < 8; ++k) {
        int i = base + k * 512 + tid;
        if (i < N) atomicAdd(&lh[labels[i]], 1);
    }
    __syncthreads();
    if (tid < 256) { int v = h[tid]; if (v) atomicAdd(&bcnt[tid], v); }
    if (tid < NT) { int v = lh[tid]; if (v) atomicAdd(&lc[tid], v); }
}

// ------- scan buckets -> boff/gcur, rowoff[N]=E; label starts (pad 64) -------
__global__ __launch_bounds__(256) void scan_master(
    const int* __restrict__ bcnt, const int* __restrict__ lc,
    int* __restrict__ boff, int* __restrict__ gcur, int* __restrict__ rowoff,
    int* __restrict__ lstart, int NB, int N, int E) {
    __shared__ int s[256];
    int tid = threadIdx.x;
    int own = (tid < NB) ? bcnt[tid] : 0;
    s[tid] = own;
    __syncthreads();
    for (int d = 1; d < 256; d <<= 1) {
        int v = (tid >= d) ? s[tid - d] : 0;
        __syncthreads();
        s[tid] += v;
        __syncthreads();
    }
    int excl = s[tid] - own;
    if (tid < NB) { boff[tid] = excl; gcur[tid] = excl; }
    if (tid == 0) {
        boff[NB] = E; rowoff[N] = E;
        int run = 0;
        for (int l = 0; l < NT; ++l) {
            lstart[l] = run;
            run += (lc[l] + 63) & ~63;
        }
    }
}

// ------- node scatter: build iperm (orig -> label-sorted slot) -------
__global__ void scatter_nodes(const int* __restrict__ labels, const int* __restrict__ lstart,
                              int* __restrict__ lcur, int* __restrict__ iperm, int N) {
    int n = blockIdx.x * 256 + threadIdx.x;
    int lab = (n < N) ? labels[n] : -1;
    int lane = threadIdx.x & 63;
    for (int l = 0; l < NT; ++l) {
        unsigned long long m = __ballot(lab == l);
        if (m == 0ull) continue;
        int leader = __builtin_ctzll(m);
        int base = 0;
        if (lane == leader) base = atomicAdd(&lcur[l], (int)__popcll(m));
        base = __shfl(base, leader, 64);
        if (lab == l) {
            int prefix = (int)__popcll(m & ((1ull << lane) - 1ull));
            iperm[n] = lstart[l] + base + prefix;
        }
    }
}

// ================= FUSE_A: scatter_edges + cast_x + cast_w_all =================
// seg 0 [0, nbEB): edge scatter into bucket regions; earr rec: x = slot|(dst&255)<<16, y = w
// seg 1 [nbEB, nbEB+nbX): cast x -> bf16 half-split slot rows
// seg 2 rest: cast W1/W2/W3 -> swizzled bf16 + permuted biases
__global__ __launch_bounds__(512) void fuse_a(
    const int* __restrict__ src, const int* __restrict__ dst, const float* __restrict__ w,
    const int* __restrict__ iperm, int* __restrict__ gcur, uint2* __restrict__ earr, int E,
    const float* __restrict__ x, unsigned short* __restrict__ actLo,
    unsigned short* __restrict__ actHi, int total4,
    const float* __restrict__ W1, const float* __restrict__ W2, const float* __restrict__ W3,
    const float* __restrict__ b1, const float* __restrict__ b2,
    unsigned short* __restrict__ W1b, unsigned short* __restrict__ W2b,
    unsigned short* __restrict__ W3b, float* __restrict__ biasPerm,
    int nbEB, int nbX) {
    int tid = threadIdx.x;
    int blk = (int)blockIdx.x;
    if (blk < nbEB) {
        // ---- edge scatter ----
        __shared__ int h[256];
        __shared__ int basearr[256];
        if (tid < 256) h[tid] = 0;
        __syncthreads();
        int base = blk * 4096;
        int b[8], rank[8], px[8]; float wv[8];
#pragma unroll
        for (int k = 0; k < 8; ++k) {
            int e = base + k * 512 + tid;
            if (e < E) {
                int d = dst[e];
                b[k] = ((unsigned)d) >> 8;
                px[k] = iperm[src[e]] | ((d & 255) << 16);
                wv[k] = w[e];
                rank[k] = atomicAdd(&h[b[k]], 1);
            } else b[k] = -1;
        }
        __syncthreads();
        if (tid < 256) { int c = h[tid]; basearr[tid] = c ? atomicAdd(&gcur[tid], c) : 0; }
        __syncthreads();
#pragma unroll
        for (int k = 0; k < 8; ++k) {
            if (b[k] >= 0) {
                int pos = basearr[b[k]] + rank[k];
                earr[pos] = make_uint2((unsigned)px[k], __float_as_uint(wv[k]));
            }
        }
    } else if (blk < nbEB + nbX) {
        // ---- cast x ----
        int i = (blk - nbEB) * 512 + tid;
        if (i < total4) {
            float4 v = ((const float4*)x)[i];
            unsigned int lo = f2bf_bits(v.x) | (f2bf_bits(v.y) << 16);
            unsigned int hi = f2bf_bits(v.z) | (f2bf_bits(v.w) << 16);
            int slot = iperm[i >> 6];
            unsigned short* dp = ((i & 63) >= 32) ? actHi : actLo;
            ((uint2*)dp)[(size_t)slot * 32 + (i & 31)] = make_uint2(lo, hi);
        }
    } else {
        // ---- cast W + biases ----
        const int S = NT * FEAT * FEAT;
        const int S3 = NT * FEAT * OUT3;
        int idx = (blk - nbEB - nbX) * 512 + tid;
        if (idx < 2 * S + S3) {
            const float* W; unsigned short* D; int OUTF; int t; bool remap;
            if (idx < S)          { W = W1; D = W1b; OUTF = FEAT; t = idx;         remap = false; }
            else if (idx < 2 * S) { W = W2; D = W2b; OUTF = FEAT; t = idx - S;     remap = true; }
            else                  { W = W3; D = W3b; OUTF = OUT3; t = idx - 2 * S; remap = true; }
            int n = t % OUTF;
            int r = t / OUTF;              // lab*256 + k_slot
            int j = r & 7, q = (r >> 3) & 3, k0 = (r >> 5) & 7, lab = r >> 8;
            int k_slot = k0 * 32 + q * 8 + j;
            int k_src = remap ? nat_of(k_slot) : k_slot;
            float f = W[((size_t)(lab * FEAT + k_src)) * OUTF + n];
            D[(((size_t)lab * 8 + k0) * OUTF + n) * 32 + q * 8 + j] = (unsigned short)f2bf_bits(f);
        } else {
            int p2 = idx - (2 * S + S3);
            if (p2 < 256) biasPerm[p2] = b1[nat_of(p2)];
            else if (p2 < 512) biasPerm[p2] = b2[nat_of(p2 - 256)];
        }
    }
}

// ------- bucket sort body (256 thr): within-bucket counting sort -> rowoff + edata -------
// final record: (w_bf16 << 16) | src_slot
__device__ void bucket_sort_body(int b, const uint2* __restrict__ earr,
                                 const int* __restrict__ boff, int* __restrict__ rowoff,
                                 unsigned int* __restrict__ edata, int N) {
    int s = boff[b], e = boff[b + 1];
    __shared__ int cnt[256], off[256];
    int tid = threadIdx.x;
    cnt[tid] = 0;
    __syncthreads();
    for (int i = s + tid; i < e; i += 256) atomicAdd(&cnt[(earr[i].x >> 16) & 255], 1);
    __syncthreads();
    off[tid] = cnt[tid];
    __syncthreads();
    for (int d = 1; d < 256; d <<= 1) {
        int v = (tid >= d) ? off[tid - d] : 0;
        __syncthreads();
        off[tid] += v;
        __syncthreads();
    }
    int excl = off[tid] - cnt[tid];
    int node = b * 256 + tid;
    if (node < N) rowoff[node] = s + excl;
    off[tid] = excl;
    __syncthreads();
    for (int i = s + tid; i < e; i += 256) {
        uint2 r = earr[i];
        int d = (r.x >> 16) & 255;
        int k = atomicAdd(&off[d], 1);
        edata[s + k] = (f2bf_bits(__uint_as_float(r.y)) << 16) | (r.x & 0xffff);
    }
}

// ------- proj 256-out body: dense 64 slots x 256 outs per block, half-split I/O -------
__device__ void proj256_body(int gb,
                             const unsigned short* __restrict__ actLo,
                             const unsigned short* __restrict__ actHi,
                             const unsigned short* __restrict__ Wswz,
                             const int* __restrict__ lstart,
                             unsigned short* __restrict__ supLo,
                             unsigned short* __restrict__ supHi) {
    int warp = threadIdx.x >> 6;
    int lane = threadIdx.x & 63;
    int m0 = gb * 64;
    int lab = (m0 >= lstart[1]) + (m0 >= lstart[2]) + (m0 >= lstart[3]);
    int q = lane >> 4, c = lane & 15;
    int n0 = warp * 64;

    const unsigned short* aLo = actLo + (size_t)(m0 + c) * 128 + q * 8;
    const unsigned short* aHi = actHi + (size_t)(m0 + c) * 128 + q * 8;
    const unsigned short* bb = Wswz + (size_t)lab * FEAT * 256 + (size_t)(n0 + c) * 32 + q * 8;

    f32x4 acc[4][4] = {};
#pragma unroll
    for (int k0 = 0; k0 < 8; ++k0) {
        const unsigned short* abase = (k0 < 4) ? aLo : aHi;
        int koff = (k0 & 3) * 32;
        bf16x8 a[4];
#pragma unroll
        for (int t = 0; t < 4; ++t) a[t] = *(const bf16x8*)(abase + (size_t)t * 2048 + koff);
        const unsigned short* bk = bb + (size_t)k0 * 32 * 256;
#pragma unroll
        for (int u = 0; u < 4; ++u) {
            bf16x8 bfrag = *(const bf16x8*)(bk + u * 512);
#pragma unroll
            for (int t = 0; t < 4; ++t)
                acc[t][u] = __builtin_amdgcn_mfma_f32_16x16x32_bf16(a[t], bfrag, acc[t][u], 0, 0, 0);
        }
    }
    // pi-store: row = m0+t*16+q*4+r ; lane writes p = n0 + c*4 + u -> half n0>>7
    uint2* ov = (uint2*)((n0 >= 128) ? supHi : supLo);
    int cix = ((n0 & 64) >> 2) + c;
#pragma unroll
    for (int t = 0; t < 4; ++t) {
#pragma unroll
        for (int r = 0; r < 4; ++r) {
            int row = m0 + t * 16 + q * 4 + r;
            unsigned int lo = f2bf_bits(acc[t][0][r]) | (f2bf_bits(acc[t][1][r]) << 16);
            unsigned int hi = f2bf_bits(acc[t][2][r]) | (f2bf_bits(acc[t][3][r]) << 16);
            ov[(size_t)row * 32 + cix] = make_uint2(lo, hi);
        }
    }
}

// ================= FUSE_B: bucket_sort (blocks [0,NB)) + proj256 L1 (rest) =================
__global__ __launch_bounds__(256) void fuse_b(
    const uint2* __restrict__ earr, const int* __restrict__ boff,
    int* __restrict__ rowoff, unsigned int* __restrict__ edata, int N, int NB,
    const unsigned short* __restrict__ actLo, const unsigned short* __restrict__ actHi,
    const unsigned short* __restrict__ Wswz, const int* __restrict__ lstart,
    unsigned short* __restrict__ supLo, unsigned short* __restrict__ supHi) {
    int blk = (int)blockIdx.x;
    if (blk < NB) bucket_sort_body(blk, earr, boff, rowoff, edata, N);
    else proj256_body(blk - NB, actLo, actHi, Wswz, lstart, supLo, supHi);
}

// ---------------- standalone proj 256 (layer 2) ----------------
__global__ __launch_bounds__(256) void proj256_kernel(
    const unsigned short* __restrict__ actLo, const unsigned short* __restrict__ actHi,
    const unsigned short* __restrict__ Wswz, const int* __restrict__ lstart,
    unsigned short* __restrict__ supLo, unsigned short* __restrict__ supHi) {
    proj256_body((int)blockIdx.x, actLo, actHi, Wswz, lstart, supLo, supHi);
}

// ---------------- proj 64-out: dense 64 slots x 64 outs per block, half-split input ------
__global__ __launch_bounds__(256) void proj64_kernel(
    const unsigned short* __restrict__ actLo, const unsigned short* __restrict__ actHi,
    const unsigned short* __restrict__ Wswz, const int* __restrict__ lstart,
    unsigned short* __restrict__ outp) {
    int warp = threadIdx.x >> 6;
    int lane = threadIdx.x & 63;
    int m0 = blockIdx.x * 64;
    int lab = (m0 >= lstart[1]) + (m0 >= lstart[2]) + (m0 >= lstart[3]);
    int q = lane >> 4, c = lane & 15;
    int mb = m0 + warp * 16;

    const unsigned short* aLo = actLo + (size_t)(mb + c) * 128 + q * 8;
    const unsigned short* aHi = actHi + (size_t)(mb + c) * 128 + q * 8;
    const unsigned short* bb = Wswz + (size_t)lab * FEAT * OUT3 + (size_t)c * 32 + q * 8;

    f32x4 acc[4] = {};
#pragma unroll
    for (int k0 = 0; k0 < 8; ++k0) {
        const unsigned short* abase = (k0 < 4) ? aLo : aHi;
        bf16x8 a = *(const bf16x8*)(abase + (k0 & 3) * 32);
        const unsigned short* bk = bb + (size_t)k0 * 32 * OUT3;
#pragma unroll
        for (int u = 0; u < 4; ++u) {
            bf16x8 bfrag = *(const bf16x8*)(bk + u * 512);
            acc[u] = __builtin_amdgcn_mfma_f32_16x16x32_bf16(a, bfrag, acc[u], 0, 0, 0);
        }
    }
    uint2* ov = (uint2*)outp;
#pragma unroll
    for (int r = 0; r < 4; ++r) {
        int row = mb + q * 4 + r;
        unsigned int lo = f2bf_bits(acc[0][r]) | (f2bf_bits(acc[1][r]) << 16);
        unsigned int hi = f2bf_bits(acc[2][r]) | (f2bf_bits(acc[3][r]) << 16);
        ov[(size_t)row * 16 + c] = make_uint2(lo, hi);
    }
}

// ------- aggregation over ONE feature half (128 feats): one wave per node, unroll 16 -----
// sup half row = 64 uints (256B). lane handles stored pos p = half*128 + 2*lane, +1.
__global__ __launch_bounds__(256) void agg256h_kernel(
    const unsigned int* __restrict__ sup, const int* __restrict__ rowoff,
    const unsigned int* __restrict__ edata, const int* __restrict__ iperm,
    const float* __restrict__ biasHalf, unsigned int* __restrict__ outp, int N) {
    int warp = __builtin_amdgcn_readfirstlane((int)(threadIdx.x >> 6));
    int node = (int)blockIdx.x * 4 + warp;
    if (node >= N) return;
    int lane = threadIdx.x & 63;
    int s = __builtin_amdgcn_readfirstlane(rowoff[node]);
    int e = __builtin_amdgcn_readfirstlane(rowoff[node + 1]);
    int slot = __builtin_amdgcn_readfirstlane(iperm[node]);
    float a0 = 0.f, a1 = 0.f;
    int j = s;
    for (; j + 16 <= e; j += 16) {
        unsigned int ed[16], v[16];
#pragma unroll
        for (int u = 0; u < 16; ++u) ed[u] = edata[j + u];
#pragma unroll
        for (int u = 0; u < 16; ++u) v[u] = sup[(size_t)(ed[u] & 0xffff) * 64 + lane];
#pragma unroll
        for (int u = 0; u < 16; ++u) {
            float w = __uint_as_float(ed[u] & 0xffff0000u);
            a0 += w * bfl(v[u]); a1 += w * bfh(v[u]);
        }
    }
    if (j < e) {   // masked tail (<=15 real edges)
        unsigned int ed[16], v[16]; float wm[16];
#pragma unroll
        for (int u = 0; u < 16; ++u) {
            int jj = j + u;
            int jc = (jj < e) ? jj : e - 1;
            ed[u] = edata[jc];
            wm[u] = (jj < e) ? __uint_as_float(ed[u] & 0xffff0000u) : 0.f;
        }
#pragma unroll
        for (int u = 0; u < 16; ++u) v[u] = sup[(size_t)(ed[u] & 0xffff) * 64 + lane];
#pragma unroll
        for (int u = 0; u < 16; ++u) { a0 += wm[u] * bfl(v[u]); a1 += wm[u] * bfh(v[u]); }
    }
    float2 b = ((const float2*)biasHalf)[lane];
    a0 = fmaxf(a0 + b.x, 0.f);
    a1 = fmaxf(a1 + b.y, 0.f);
    outp[(size_t)slot * 64 + lane] = f2bf_bits(a0) | (f2bf_bits(a1) << 16);
}

// ---------------- aggregation, 64-feat: one wave per node (lane = stored pos), fp32 out --
__global__ __launch_bounds__(256) void agg64_kernel(
    const unsigned short* __restrict__ sup, const int* __restrict__ rowoff,
    const unsigned int* __restrict__ edata, const float* __restrict__ b3,
    float* __restrict__ outp, int N) {
    int warp = __builtin_amdgcn_readfirstlane((int)(threadIdx.x >> 6));
    int node = (int)blockIdx.x * 4 + warp;
    if (node >= N) return;
    int lane = threadIdx.x & 63;
    int s = __builtin_amdgcn_readfirstlane(rowoff[node]);
    int e = __builtin_amdgcn_readfirstlane(rowoff[node + 1]);
    float a = 0.f;
    int j = s;
    for (; j + 8 <= e; j += 8) {
        unsigned int ed[8]; unsigned short v[8];
#pragma unroll
        for (int u = 0; u < 8; ++u) ed[u] = edata[j + u];
#pragma unroll
        for (int u = 0; u < 8; ++u) v[u] = sup[(size_t)(ed[u] & 0xffff) * 64 + lane];
#pragma unroll
        for (int u = 0; u < 8; ++u)
            a += __uint_as_float(ed[u] & 0xffff0000u) * __uint_as_float((unsigned int)v[u] << 16);
    }
    if (j < e) {
        unsigned int ed[8]; float wm[8]; unsigned short v[8];
#pragma unroll
        for (int u = 0; u < 8; ++u) {
            int jj = j + u;
            int jc = (jj < e) ? jj : e - 1;
            ed[u] = edata[jc];
            wm[u] = (jj < e) ? __uint_as_float(ed[u] & 0xffff0000u) : 0.f;
        }
#pragma unroll
        for (int u = 0; u < 8; ++u) v[u] = sup[(size_t)(ed[u] & 0xffff) * 64 + lane];
#pragma unroll
        for (int u = 0; u < 8; ++u)
            a += wm[u] * __uint_as_float((unsigned int)v[u] << 16);
    }
    int natp = (((lane & 3) << 4) | (lane >> 2));    // un-permute pi within the 64 outs
    outp[(size_t)node * 64 + natp] = a + b3[natp];
}

extern "C" void kernel_launch(void* const* d_in, const int* in_sizes, int n_in,
                              void* d_out, int out_size, void* d_ws, size_t ws_size,
                              hipStream_t stream) {
    const float* x        = (const float*)d_in[0];
    const int*   edge_src = (const int*)d_in[1];
    const int*   edge_dst = (const int*)d_in[2];
    const float* edge_w   = (const float*)d_in[3];
    const int*   labels   = (const int*)d_in[4];
    const float* W1 = (const float*)d_in[5];
    const float* b1 = (const float*)d_in[6];
    const float* W2 = (const float*)d_in[7];
    const float* b2 = (const float*)d_in[8];
    const float* W3 = (const float*)d_in[9];
    const float* b3 = (const float*)d_in[10];

    const int N = in_sizes[0] / FEAT;
    const int E = in_sizes[1];
    const int NB = (N + 255) >> 8;                    // dst buckets (orig id space)
    const int G64 = (N + NT * 64 + 63) / 64;          // slot-space 64-row tiles (upper bound)
    const int slotCap = G64 * 64;

    // ---- workspace carve (256B aligned) ----
    char* p = (char*)d_ws;
    auto alloc = [&](size_t bytes) -> char* {
        char* r = p;
        p += (bytes + 255) & ~(size_t)255;
        return r;
    };
    unsigned short* bufA = (unsigned short*)alloc((size_t)slotCap * FEAT * 2);
    unsigned short* bufB = (unsigned short*)alloc((size_t)slotCap * FEAT * 2);
    unsigned short* W1b  = (unsigned short*)alloc((size_t)NT * FEAT * FEAT * 2);
    unsigned short* W2b  = (unsigned short*)alloc((size_t)NT * FEAT * FEAT * 2);
    unsigned short* W3b  = (unsigned short*)alloc((size_t)NT * FEAT * OUT3 * 2);
    float*        biasPerm = (float*)alloc(512 * 4);
    int*          rowoff = (int*)alloc((size_t)(N + 1) * 4);
    unsigned int* edata  = (unsigned int*)alloc((size_t)E * 4);
    int*          iperm  = (int*)alloc((size_t)N * 4);
    int*          counters = (int*)alloc(264 * 4);    // bcnt[256] + lc[4] + lcur[4]
    int*          boff   = (int*)alloc(257 * 4);
    int*          gcur   = (int*)alloc(256 * 4);
    int*          lstart = (int*)alloc(64);
    int* bcnt = counters;
    int* lc   = counters + 256;
    int* lcur = counters + 260;

    // half-table views (lo = feats p<128, hi = p>=128), each slotCap*128 ushorts
    unsigned short* actLo = bufA;
    unsigned short* actHi = bufA + (size_t)slotCap * 128;
    unsigned short* supLo = bufB;
    unsigned short* supHi = bufB + (size_t)slotCap * 128;
    // bucket-sort staging ALIASED onto d_out (N*OUT3*4 = 12.8MB = E*8; d_out written
    // only by the final agg64, and earr is fully overwritten by scatter before reads)
    uint2* earr = (uint2*)d_out;

    const int nbEB = (E + 4095) / 4096;
    const int total4 = N * 64;                        // float4 groups in x
    const int nbX = (total4 + 511) / 512;
    const int totW = 2 * NT * FEAT * FEAT + NT * FEAT * OUT3 + 512;
    const int nbW = (totW + 511) / 512;

    // ---- CSR build + label-sort + casts ----
    hipMemsetAsync(counters, 0, 264 * 4, stream);
    pass_a<<<nbEB, 512, 0, stream>>>(edge_dst, labels, bcnt, lc, E, N);
    scan_master<<<1, 256, 0, stream>>>(bcnt, lc, boff, gcur, rowoff, lstart, NB, N, E);
    scatter_nodes<<<(N + 255) / 256, 256, 0, stream>>>(labels, lstart, lcur, iperm, N);
    fuse_a<<<nbEB + nbX + nbW, 512, 0, stream>>>(
        edge_src, edge_dst, edge_w, iperm, gcur, earr, E,
        x, actLo, actHi, total4,
        W1, W2, W3, b1, b2, W1b, W2b, W3b, biasPerm, nbEB, nbX);

    const int aggGrid = (N + 3) / 4;
    // ---- layer 1 (bucket_sort overlapped with proj256-L1) ----
    fuse_b<<<NB + G64, 256, 0, stream>>>(earr, boff, rowoff, edata, N, NB,
                                         actLo, actHi, W1b, lstart, supLo, supHi);
    agg256h_kernel<<<aggGrid, 256, 0, stream>>>((const unsigned int*)supLo, rowoff, edata, iperm,
                                                biasPerm + 0, (unsigned int*)actLo, N);
    agg256h_kernel<<<aggGrid, 256, 0, stream>>>((const unsigned int*)supHi, rowoff, edata, iperm,
                                                biasPerm + 128, (unsigned int*)actHi, N);
    // ---- layer 2 ----
    proj256_kernel<<<G64, 256, 0, stream>>>(actLo, actHi, W2b, lstart, supLo, supHi);
    agg256h_kernel<<<aggGrid, 256, 0, stream>>>((const unsigned int*)supLo, rowoff, edata, iperm,
                                                biasPerm + 256, (unsigned int*)actLo, N);
    agg256h_kernel<<<aggGrid, 256, 0, stream>>>((const unsigned int*)supHi, rowoff, edata, iperm,
                                                biasPerm + 384, (unsigned int*)actHi, N);
    // ---- layer 3 ----
    proj64_kernel<<<G64, 256, 0, stream>>>(actLo, actHi, W3b, lstart, bufB);
    agg64_kernel<<<aggGrid, 256, 0, stream>>>(bufB, rowoff, edata, b3, (float*)d_out, N);
}